// Round 1
// baseline (1493.591 us; speedup 1.0000x reference)
//
#include <hip/hip_runtime.h>
#include <math.h>

// ---------------------------------------------------------------------------
// Problem constants (match reference): N=50000, E=800000, IN=256, HID=128,
// OUT=128.  Edge list gets N self-loops appended -> Etot = E + N.
// ---------------------------------------------------------------------------

#define NEG_SLOPE 0.2f
#define EPS_DEN 1e-16f

// ===========================================================================
// GEMM: C[n x M] = act(A[n x K] @ B[K x M] + bias)
// 64x64 block tile, 16x16 threads, 4x4 microtile. ACT: 0=none, 1=relu
// K must be a multiple of 16, M a multiple of 64.
// ===========================================================================
template <int ACT>
__global__ __launch_bounds__(256) void gemm_kernel(
    const float* __restrict__ A, const float* __restrict__ B,
    const float* __restrict__ bias, float* __restrict__ C,
    int n, int K, int M) {
  __shared__ float As[16][65];  // [k][m]
  __shared__ float Bs[16][65];  // [k][c]
  const int tx = threadIdx.x, ty = threadIdx.y;
  const int tid = ty * 16 + tx;
  const int row0 = blockIdx.x * 64;
  const int col0 = blockIdx.y * 64;
  float acc[4][4] = {};
  const int am = tid >> 2, ak = (tid & 3) * 4;    // A tile: 64 rows x 16 k
  const int bk = tid >> 4, bc = (tid & 15) * 4;   // B tile: 16 k x 64 cols
  for (int k0 = 0; k0 < K; k0 += 16) {
    int arow = row0 + am;
    float4 av = make_float4(0.f, 0.f, 0.f, 0.f);
    if (arow < n) av = *(const float4*)(A + (size_t)arow * K + k0 + ak);
    As[ak + 0][am] = av.x; As[ak + 1][am] = av.y;
    As[ak + 2][am] = av.z; As[ak + 3][am] = av.w;
    float4 bv = *(const float4*)(B + (size_t)(k0 + bk) * M + col0 + bc);
    Bs[bk][bc + 0] = bv.x; Bs[bk][bc + 1] = bv.y;
    Bs[bk][bc + 2] = bv.z; Bs[bk][bc + 3] = bv.w;
    __syncthreads();
#pragma unroll
    for (int kk = 0; kk < 16; kk++) {
      float a[4], b[4];
#pragma unroll
      for (int i = 0; i < 4; i++) a[i] = As[kk][ty * 4 + i];
#pragma unroll
      for (int j = 0; j < 4; j++) b[j] = Bs[kk][tx * 4 + j];
#pragma unroll
      for (int i = 0; i < 4; i++)
#pragma unroll
        for (int j = 0; j < 4; j++) acc[i][j] += a[i] * b[j];
    }
    __syncthreads();
  }
#pragma unroll
  for (int i = 0; i < 4; i++) {
    int row = row0 + ty * 4 + i;
    if (row >= n) continue;
#pragma unroll
    for (int j = 0; j < 4; j++) {
      int col = col0 + tx * 4 + j;
      float v = acc[i][j] + (bias ? bias[col] : 0.f);
      if (ACT == 1) v = v > 0.f ? v : 0.f;
      C[(size_t)row * M + col] = v;
    }
  }
}

// ===========================================================================
// Per-node attention logits: alpha_s[i][h] = sum_c proj[i][h][c]*a_src[h][c]
// One wave per node.  H<=4, C in {64,128}, H*C in {128,256}.
// ===========================================================================
__global__ __launch_bounds__(256) void alpha_kernel(
    const float* __restrict__ proj, const float* __restrict__ a_s,
    const float* __restrict__ a_d, float* __restrict__ alpha_s,
    float* __restrict__ alpha_d, int n, int H, int C) {
  int wid = (blockIdx.x * blockDim.x + threadIdx.x) >> 6;
  int lane = threadIdx.x & 63;
  if (wid >= n) return;
  int HC = H * C;
  const float* pr = proj + (size_t)wid * HC;
  float ps[4] = {0.f, 0.f, 0.f, 0.f};
  float pd[4] = {0.f, 0.f, 0.f, 0.f};
  for (int ch = lane; ch < HC; ch += 64) {
    int h = ch / C;
    float v = pr[ch];
    ps[h] += v * a_s[ch];
    pd[h] += v * a_d[ch];
  }
#pragma unroll
  for (int off = 32; off; off >>= 1) {
#pragma unroll
    for (int h = 0; h < 4; h++) {
      ps[h] += __shfl_xor(ps[h], off, 64);
      pd[h] += __shfl_xor(pd[h], off, 64);
    }
  }
  if (lane == 0) {
    for (int h = 0; h < H; h++) {
      alpha_s[(size_t)wid * H + h] = ps[h];
      alpha_d[(size_t)wid * H + h] = pd[h];
    }
  }
}

// ===========================================================================
// CSR build: deg histogram -> exclusive scan -> scatter src ids per dst
// ===========================================================================
__global__ void zero_int_kernel(int* __restrict__ p, int n) {
  int i = blockIdx.x * blockDim.x + threadIdx.x;
  if (i < n) p[i] = 0;
}

__global__ void count_deg_kernel(const int* __restrict__ edst,
                                 int* __restrict__ deg, int E, int n) {
  int i = blockIdx.x * blockDim.x + threadIdx.x;
  if (i >= E + n) return;
  int d = (i < E) ? edst[i] : (i - E);  // self-loop for i >= E
  if ((unsigned)d < (unsigned)n) atomicAdd(&deg[d], 1);
}

__global__ __launch_bounds__(1024) void scan_kernel(
    const int* __restrict__ deg, int* __restrict__ rowptr,
    int* __restrict__ cursor, int n) {
  __shared__ int sums[1024];
  int t = threadIdx.x;
  int chunk = (n + 1023) / 1024;
  int start = t * chunk;
  int end = start + chunk; if (end > n) end = n;
  int s = 0;
  for (int i = start; i < end; i++) s += deg[i];
  sums[t] = s;
  __syncthreads();
  for (int off = 1; off < 1024; off <<= 1) {
    int v = 0;
    if (t >= off) v = sums[t - off];
    __syncthreads();
    if (t >= off) sums[t] += v;
    __syncthreads();
  }
  int excl = (t == 0) ? 0 : sums[t - 1];
  for (int i = start; i < end; i++) {
    rowptr[i] = excl;
    cursor[i] = excl;
    excl += deg[i];
  }
  if (t == 1023) rowptr[n] = sums[1023];
}

__global__ void scatter_kernel(const int* __restrict__ esrc,
                               const int* __restrict__ edst,
                               int* __restrict__ cursor,
                               int* __restrict__ csr_src, int E, int n) {
  int i = blockIdx.x * blockDim.x + threadIdx.x;
  int tot = E + n;
  if (i >= tot) return;
  int s, d;
  if (i < E) { s = esrc[i]; d = edst[i]; } else { s = d = i - E; }
  if ((unsigned)d >= (unsigned)n || (unsigned)s >= (unsigned)n) return;
  int pos = atomicAdd(&cursor[d], 1);
  if (pos < tot) csr_src[pos] = s;
}

// ===========================================================================
// GAT aggregation with segment softmax.
//   CONCAT=true : one wave per (dst,head); out[dst][h*C + c], bias+act fused
//   CONCAT=false: one wave per dst, mean over heads; out[dst][c]
//   ACT: 0=none, 1=elu
// C is 64 (CPL=1) or 128 (CPL=2); wave-uniform loop over incoming edges.
// ===========================================================================
template <bool CONCAT, int ACT>
__global__ __launch_bounds__(256) void gat_agg_kernel(
    const float* __restrict__ proj, const float* __restrict__ alpha_s,
    const float* __restrict__ alpha_d, const int* __restrict__ rowptr,
    const int* __restrict__ csr_src, const float* __restrict__ bias,
    float* __restrict__ out, int n, int H, int C) {
  int wid = (blockIdx.x * blockDim.x + threadIdx.x) >> 6;
  int lane = threadIdx.x & 63;
  const int CPL = C >> 6;  // channels per lane: 1 or 2
  const int HC = H * C;

  int dst, h_begin, h_end;
  if (CONCAT) {
    if (wid >= n * H) return;
    dst = wid / H;
    h_begin = wid - dst * H;
    h_end = h_begin + 1;
  } else {
    if (wid >= n) return;
    dst = wid;
    h_begin = 0;
    h_end = H;
  }

  const int rs = rowptr[dst], re = rowptr[dst + 1];
  float accm0 = 0.f, accm1 = 0.f;  // mean accumulators (non-concat)

  for (int h = h_begin; h < h_end; h++) {
    float adv = alpha_d[(size_t)dst * H + h];
    // pass 1: segment max (lane-parallel)
    float m = -INFINITY;
    for (int i = rs + lane; i < re; i += 64) {
      int s = csr_src[i];
      float e = alpha_s[(size_t)s * H + h] + adv;
      e = e > 0.f ? e : NEG_SLOPE * e;
      m = fmaxf(m, e);
    }
#pragma unroll
    for (int off = 32; off; off >>= 1) m = fmaxf(m, __shfl_xor(m, off, 64));
    // pass 2: wave-uniform loop; accumulate exp * proj[src] and denom
    float denom = 0.f, a0 = 0.f, a1 = 0.f;
    for (int i = rs; i < re; i++) {
      int s = csr_src[i];
      float e = alpha_s[(size_t)s * H + h] + adv;
      e = e > 0.f ? e : NEG_SLOPE * e;
      float ex = __expf(e - m);
      denom += ex;
      const float* pr = proj + (size_t)s * HC + h * C;
      a0 += ex * pr[lane];
      if (CPL == 2) a1 += ex * pr[lane + 64];
    }
    float inv = 1.f / (denom + EPS_DEN);
    if (CONCAT) {
      int ch = h * C + lane;
      float v = a0 * inv + bias[ch];
      if (ACT == 1) v = v > 0.f ? v : (__expf(v) - 1.f);
      out[(size_t)dst * HC + ch] = v;
      if (CPL == 2) {
        int ch2 = h * C + 64 + lane;
        float v2 = a1 * inv + bias[ch2];
        if (ACT == 1) v2 = v2 > 0.f ? v2 : (__expf(v2) - 1.f);
        out[(size_t)dst * HC + ch2] = v2;
      }
    } else {
      accm0 += a0 * inv;
      accm1 += a1 * inv;
    }
  }

  if (!CONCAT) {
    float invH = 1.f / (float)H;
    float v = accm0 * invH + bias[lane];
    if (ACT == 1) v = v > 0.f ? v : (__expf(v) - 1.f);
    out[(size_t)dst * C + lane] = v;
    if (CPL == 2) {
      float v2 = accm1 * invH + bias[64 + lane];
      if (ACT == 1) v2 = v2 > 0.f ? v2 : (__expf(v2) - 1.f);
      out[(size_t)dst * C + 64 + lane] = v2;
    }
  }
}

// ===========================================================================
// Host side
// ===========================================================================
extern "C" void kernel_launch(void* const* d_in, const int* in_sizes, int n_in,
                              void* d_out, int out_size, void* d_ws,
                              size_t ws_size, hipStream_t stream) {
  const float* x    = (const float*)d_in[0];
  const int*   ei   = (const int*)d_in[1];
  const float* W1   = (const float*)d_in[2];
  const float* b1   = (const float*)d_in[3];
  const float* W2   = (const float*)d_in[4];
  const float* b2   = (const float*)d_in[5];
  const float* g1W  = (const float*)d_in[6];
  const float* g1as = (const float*)d_in[7];
  const float* g1ad = (const float*)d_in[8];
  const float* g1b  = (const float*)d_in[9];
  const float* g2W  = (const float*)d_in[10];
  const float* g2as = (const float*)d_in[11];
  const float* g2ad = (const float*)d_in[12];
  const float* g2b  = (const float*)d_in[13];
  const float* g3W  = (const float*)d_in[14];
  const float* g3as = (const float*)d_in[15];
  const float* g3ad = (const float*)d_in[16];
  const float* g3b  = (const float*)d_in[17];

  const int N = in_sizes[0] / 256;   // 50000
  const int E = in_sizes[1] / 2;     // 800000
  const int Etot = E + N;

  // Workspace layout (floats)
  float* ws = (float*)d_ws;
  size_t off = 0;
  float* bufA = ws + off; off += (size_t)N * 256;  // projection buffer
  float* bufB = ws + off; off += (size_t)N * 256;  // feature buffer (wide)
  float* bufC = ws + off; off += (size_t)N * 128;  // feature buffer (narrow)
  float* alS  = ws + off; off += (size_t)N * 4;
  float* alD  = ws + off; off += (size_t)N * 4;
  int* ibase  = (int*)(ws + off);
  int* deg    = ibase;               // N
  int* rowptr = deg + N;             // N+1
  int* cursor = rowptr + N + 1;      // N
  int* csrsrc = cursor + N;          // Etot

  const int* esrc = ei;
  const int* edst = ei + E;

  dim3 blk16(16, 16);

  // ---- CSR build (edge structure shared by all 3 GAT layers) ----
  zero_int_kernel<<<(N + 255) / 256, 256, 0, stream>>>(deg, N);
  count_deg_kernel<<<(Etot + 255) / 256, 256, 0, stream>>>(edst, deg, E, N);
  scan_kernel<<<1, 1024, 0, stream>>>(deg, rowptr, cursor, N);
  scatter_kernel<<<(Etot + 255) / 256, 256, 0, stream>>>(esrc, edst, cursor,
                                                         csrsrc, E, N);

  // ---- MLP ----
  // h1 = relu(x @ W1 + b1): [N,256]@[256,128] -> bufB (dense N x 128)
  gemm_kernel<1><<<dim3((N + 63) / 64, 128 / 64), blk16, 0, stream>>>(
      x, W1, b1, bufB, N, 256, 128);
  // h2 = relu(h1 @ W2 + b2): [N,128]@[128,128] -> bufC
  gemm_kernel<1><<<dim3((N + 63) / 64, 128 / 64), blk16, 0, stream>>>(
      bufB, W2, b2, bufC, N, 128, 128);

  // ---- GAT1: 128 -> 4 heads x 64, concat, ELU ----
  gemm_kernel<0><<<dim3((N + 63) / 64, 256 / 64), blk16, 0, stream>>>(
      bufC, g1W, nullptr, bufA, N, 128, 256);
  alpha_kernel<<<(N + 3) / 4, 256, 0, stream>>>(bufA, g1as, g1ad, alS, alD, N,
                                                4, 64);
  gat_agg_kernel<true, 1><<<((size_t)N * 4 + 3) / 4, 256, 0, stream>>>(
      bufA, alS, alD, rowptr, csrsrc, g1b, bufB, N, 4, 64);

  // ---- GAT2: 256 -> 2 heads x 128, mean, ELU ----
  gemm_kernel<0><<<dim3((N + 63) / 64, 256 / 64), blk16, 0, stream>>>(
      bufB, g2W, nullptr, bufA, N, 256, 256);
  alpha_kernel<<<(N + 3) / 4, 256, 0, stream>>>(bufA, g2as, g2ad, alS, alD, N,
                                                2, 128);
  gat_agg_kernel<false, 1><<<(N + 3) / 4, 256, 0, stream>>>(
      bufA, alS, alD, rowptr, csrsrc, g2b, bufC, N, 2, 128);

  // ---- GAT3: 128 -> 1 head x 128, mean, no act -> d_out ----
  gemm_kernel<0><<<dim3((N + 63) / 64, 128 / 64), blk16, 0, stream>>>(
      bufC, g3W, nullptr, bufA, N, 128, 128);
  alpha_kernel<<<(N + 3) / 4, 256, 0, stream>>>(bufA, g3as, g3ad, alS, alD, N,
                                                1, 128);
  gat_agg_kernel<false, 0><<<(N + 3) / 4, 256, 0, stream>>>(
      bufA, alS, alD, rowptr, csrsrc, g3b, (float*)d_out, N, 1, 128);
}

// Round 2
// 1076.667 us; speedup vs baseline: 1.3872x; 1.3872x over previous
//
#include <hip/hip_runtime.h>
#include <math.h>

// ---------------------------------------------------------------------------
// Problem constants (match reference): N=50000, E=800000, IN=256, HID=128,
// OUT=128.  Edge list gets N self-loops appended -> Etot = E + N.
// ---------------------------------------------------------------------------

#define NEG_SLOPE 0.2f
#define EPS_DEN 1e-16f

// ===========================================================================
// GEMM: C[n x M] = act(A[n x K] @ B[K x M] + bias)
// 64x64 block tile, 16x16 threads, 4x4 microtile. ACT: 0=none, 1=relu
// K must be a multiple of 16, M a multiple of 64.
// ===========================================================================
template <int ACT>
__global__ __launch_bounds__(256) void gemm_kernel(
    const float* __restrict__ A, const float* __restrict__ B,
    const float* __restrict__ bias, float* __restrict__ C,
    int n, int K, int M) {
  __shared__ float As[16][65];  // [k][m]
  __shared__ float Bs[16][65];  // [k][c]
  const int tx = threadIdx.x, ty = threadIdx.y;
  const int tid = ty * 16 + tx;
  const int row0 = blockIdx.x * 64;
  const int col0 = blockIdx.y * 64;
  float acc[4][4] = {};
  const int am = tid >> 2, ak = (tid & 3) * 4;    // A tile: 64 rows x 16 k
  const int bk = tid >> 4, bc = (tid & 15) * 4;   // B tile: 16 k x 64 cols
  for (int k0 = 0; k0 < K; k0 += 16) {
    int arow = row0 + am;
    float4 av = make_float4(0.f, 0.f, 0.f, 0.f);
    if (arow < n) av = *(const float4*)(A + (size_t)arow * K + k0 + ak);
    As[ak + 0][am] = av.x; As[ak + 1][am] = av.y;
    As[ak + 2][am] = av.z; As[ak + 3][am] = av.w;
    float4 bv = *(const float4*)(B + (size_t)(k0 + bk) * M + col0 + bc);
    Bs[bk][bc + 0] = bv.x; Bs[bk][bc + 1] = bv.y;
    Bs[bk][bc + 2] = bv.z; Bs[bk][bc + 3] = bv.w;
    __syncthreads();
#pragma unroll
    for (int kk = 0; kk < 16; kk++) {
      float a[4], b[4];
#pragma unroll
      for (int i = 0; i < 4; i++) a[i] = As[kk][ty * 4 + i];
#pragma unroll
      for (int j = 0; j < 4; j++) b[j] = Bs[kk][tx * 4 + j];
#pragma unroll
      for (int i = 0; i < 4; i++)
#pragma unroll
        for (int j = 0; j < 4; j++) acc[i][j] += a[i] * b[j];
    }
    __syncthreads();
  }
#pragma unroll
  for (int i = 0; i < 4; i++) {
    int row = row0 + ty * 4 + i;
    if (row >= n) continue;
#pragma unroll
    for (int j = 0; j < 4; j++) {
      int col = col0 + tx * 4 + j;
      float v = acc[i][j] + (bias ? bias[col] : 0.f);
      if (ACT == 1) v = v > 0.f ? v : 0.f;
      C[(size_t)row * M + col] = v;
    }
  }
}

// ===========================================================================
// Per-node attention logits: alpha_s[i][h] = sum_c proj[i][h][c]*a_src[h][c]
// One wave per node.  H<=4, C in {64,128}, H*C in {128,256}.
// ===========================================================================
__global__ __launch_bounds__(256) void alpha_kernel(
    const float* __restrict__ proj, const float* __restrict__ a_s,
    const float* __restrict__ a_d, float* __restrict__ alpha_s,
    float* __restrict__ alpha_d, int n, int H, int C) {
  int wid = (blockIdx.x * blockDim.x + threadIdx.x) >> 6;
  int lane = threadIdx.x & 63;
  if (wid >= n) return;
  int HC = H * C;
  const float* pr = proj + (size_t)wid * HC;
  float ps[4] = {0.f, 0.f, 0.f, 0.f};
  float pd[4] = {0.f, 0.f, 0.f, 0.f};
  for (int ch = lane; ch < HC; ch += 64) {
    int h = ch / C;
    float v = pr[ch];
    ps[h] += v * a_s[ch];
    pd[h] += v * a_d[ch];
  }
#pragma unroll
  for (int off = 32; off; off >>= 1) {
#pragma unroll
    for (int h = 0; h < 4; h++) {
      ps[h] += __shfl_xor(ps[h], off, 64);
      pd[h] += __shfl_xor(pd[h], off, 64);
    }
  }
  if (lane == 0) {
    for (int h = 0; h < H; h++) {
      alpha_s[(size_t)wid * H + h] = ps[h];
      alpha_d[(size_t)wid * H + h] = pd[h];
    }
  }
}

// ===========================================================================
// CSR build: deg histogram -> exclusive scan -> scatter src ids per dst
// ===========================================================================
__global__ void zero_int_kernel(int* __restrict__ p, int n) {
  int i = blockIdx.x * blockDim.x + threadIdx.x;
  if (i < n) p[i] = 0;
}

__global__ void count_deg_kernel(const int* __restrict__ edst,
                                 int* __restrict__ deg, int E, int n) {
  int i = blockIdx.x * blockDim.x + threadIdx.x;
  if (i >= E + n) return;
  int d = (i < E) ? edst[i] : (i - E);  // self-loop for i >= E
  if ((unsigned)d < (unsigned)n) atomicAdd(&deg[d], 1);
}

__global__ __launch_bounds__(1024) void scan_kernel(
    const int* __restrict__ deg, int* __restrict__ rowptr,
    int* __restrict__ cursor, int n) {
  __shared__ int sums[1024];
  int t = threadIdx.x;
  int chunk = (n + 1023) / 1024;
  int start = t * chunk;
  int end = start + chunk; if (end > n) end = n;
  int s = 0;
  for (int i = start; i < end; i++) s += deg[i];
  sums[t] = s;
  __syncthreads();
  for (int off = 1; off < 1024; off <<= 1) {
    int v = 0;
    if (t >= off) v = sums[t - off];
    __syncthreads();
    if (t >= off) sums[t] += v;
    __syncthreads();
  }
  int excl = (t == 0) ? 0 : sums[t - 1];
  for (int i = start; i < end; i++) {
    rowptr[i] = excl;
    cursor[i] = excl;
    excl += deg[i];
  }
  if (t == 1023) rowptr[n] = sums[1023];
}

__global__ void scatter_kernel(const int* __restrict__ esrc,
                               const int* __restrict__ edst,
                               int* __restrict__ cursor,
                               int* __restrict__ csr_src, int E, int n) {
  int i = blockIdx.x * blockDim.x + threadIdx.x;
  int tot = E + n;
  if (i >= tot) return;
  int s, d;
  if (i < E) { s = esrc[i]; d = edst[i]; } else { s = d = i - E; }
  if ((unsigned)d >= (unsigned)n || (unsigned)s >= (unsigned)n) return;
  int pos = atomicAdd(&cursor[d], 1);
  if (pos < tot) csr_src[pos] = s;
}

// ===========================================================================
// GAT aggregation with segment softmax — edge-parallel subgroup version.
// One wave per dst node, processing ALL heads per edge.
//   C=64  -> 4 subgroups of 16 lanes: 4 edges in flight, lane = 4 channels
//   C=128 -> 2 subgroups of 32 lanes: 2 edges in flight, lane = 4 channels
// Per edge, a subgroup loads the full proj row (H x C) via float4s -> up to
// NSUB*H outstanding 16B loads per wave vs 1 in the serial version.
//   CONCAT: out[dst][h*C+c]; else mean over heads -> out[dst][c]
//   ACT: 0=none, 1=elu
// ===========================================================================
template <int H, int C, bool CONCAT, int ACT>
__global__ __launch_bounds__(256) void gat_agg_kernel(
    const float* __restrict__ proj, const float* __restrict__ alpha_s,
    const float* __restrict__ alpha_d, const int* __restrict__ rowptr,
    const int* __restrict__ csr_src, const float* __restrict__ bias,
    float* __restrict__ out, int n) {
  constexpr int SUBW = C / 4;      // lanes per subgroup (16 or 32)
  constexpr int NSUB = 64 / SUBW;  // concurrent edges per wave (4 or 2)
  constexpr int HC = H * C;

  const int wid = (blockIdx.x * blockDim.x + threadIdx.x) >> 6;
  const int lane = threadIdx.x & 63;
  if (wid >= n) return;
  const int dst = wid;
  const int sub = lane / SUBW;
  const int sl = lane % SUBW;  // channels sl*4 .. sl*4+3 of each head

  float adv[H];
#pragma unroll
  for (int h = 0; h < H; h++) adv[h] = alpha_d[(size_t)dst * H + h];

  const int rs = rowptr[dst], re = rowptr[dst + 1];

  // ---- pass 1: per-head segment max (lane-parallel over edges) ----
  float m[H];
#pragma unroll
  for (int h = 0; h < H; h++) m[h] = -INFINITY;
  for (int i = rs + lane; i < re; i += 64) {
    int s = csr_src[i];
#pragma unroll
    for (int h = 0; h < H; h++) {
      float e = alpha_s[(size_t)s * H + h] + adv[h];
      e = e > 0.f ? e : NEG_SLOPE * e;
      m[h] = fmaxf(m[h], e);
    }
  }
#pragma unroll
  for (int off = 32; off; off >>= 1)
#pragma unroll
    for (int h = 0; h < H; h++) m[h] = fmaxf(m[h], __shfl_xor(m[h], off, 64));

  // ---- pass 2: subgroup-parallel edge loop ----
  float denom[H];
  float4 acc[H];
#pragma unroll
  for (int h = 0; h < H; h++) {
    denom[h] = 0.f;
    acc[h] = make_float4(0.f, 0.f, 0.f, 0.f);
  }
  for (int i = rs + sub; i < re; i += NSUB) {
    int s = csr_src[i];
    const float* pr = proj + (size_t)s * HC + sl * 4;
#pragma unroll
    for (int h = 0; h < H; h++) {
      float e = alpha_s[(size_t)s * H + h] + adv[h];
      e = e > 0.f ? e : NEG_SLOPE * e;
      float ex = __expf(e - m[h]);
      denom[h] += ex;
      float4 pv = *(const float4*)(pr + h * C);
      acc[h].x += ex * pv.x;
      acc[h].y += ex * pv.y;
      acc[h].z += ex * pv.z;
      acc[h].w += ex * pv.w;
    }
  }
  // combine subgroups: lanes l, l^SUBW(, l^2SUBW) share the same channels
#pragma unroll
  for (int off = SUBW; off < 64; off <<= 1) {
#pragma unroll
    for (int h = 0; h < H; h++) {
      denom[h] += __shfl_xor(denom[h], off, 64);
      acc[h].x += __shfl_xor(acc[h].x, off, 64);
      acc[h].y += __shfl_xor(acc[h].y, off, 64);
      acc[h].z += __shfl_xor(acc[h].z, off, 64);
      acc[h].w += __shfl_xor(acc[h].w, off, 64);
    }
  }

  if (sub != 0) return;  // all subgroups hold identical sums now

  if (CONCAT) {
#pragma unroll
    for (int h = 0; h < H; h++) {
      float inv = 1.f / (denom[h] + EPS_DEN);
      const float4 bv = *(const float4*)(bias + h * C + sl * 4);
      float4 v;
      v.x = acc[h].x * inv + bv.x;
      v.y = acc[h].y * inv + bv.y;
      v.z = acc[h].z * inv + bv.z;
      v.w = acc[h].w * inv + bv.w;
      if (ACT == 1) {
        v.x = v.x > 0.f ? v.x : (__expf(v.x) - 1.f);
        v.y = v.y > 0.f ? v.y : (__expf(v.y) - 1.f);
        v.z = v.z > 0.f ? v.z : (__expf(v.z) - 1.f);
        v.w = v.w > 0.f ? v.w : (__expf(v.w) - 1.f);
      }
      *(float4*)(out + (size_t)dst * HC + h * C + sl * 4) = v;
    }
  } else {
    float4 sumv = make_float4(0.f, 0.f, 0.f, 0.f);
#pragma unroll
    for (int h = 0; h < H; h++) {
      float inv = 1.f / (denom[h] + EPS_DEN);
      sumv.x += acc[h].x * inv;
      sumv.y += acc[h].y * inv;
      sumv.z += acc[h].z * inv;
      sumv.w += acc[h].w * inv;
    }
    const float invH = 1.f / (float)H;
    const float4 bv = *(const float4*)(bias + sl * 4);
    float4 v;
    v.x = sumv.x * invH + bv.x;
    v.y = sumv.y * invH + bv.y;
    v.z = sumv.z * invH + bv.z;
    v.w = sumv.w * invH + bv.w;
    if (ACT == 1) {
      v.x = v.x > 0.f ? v.x : (__expf(v.x) - 1.f);
      v.y = v.y > 0.f ? v.y : (__expf(v.y) - 1.f);
      v.z = v.z > 0.f ? v.z : (__expf(v.z) - 1.f);
      v.w = v.w > 0.f ? v.w : (__expf(v.w) - 1.f);
    }
    *(float4*)(out + (size_t)dst * C + sl * 4) = v;
  }
}

// ===========================================================================
// Host side
// ===========================================================================
extern "C" void kernel_launch(void* const* d_in, const int* in_sizes, int n_in,
                              void* d_out, int out_size, void* d_ws,
                              size_t ws_size, hipStream_t stream) {
  const float* x    = (const float*)d_in[0];
  const int*   ei   = (const int*)d_in[1];
  const float* W1   = (const float*)d_in[2];
  const float* b1   = (const float*)d_in[3];
  const float* W2   = (const float*)d_in[4];
  const float* b2   = (const float*)d_in[5];
  const float* g1W  = (const float*)d_in[6];
  const float* g1as = (const float*)d_in[7];
  const float* g1ad = (const float*)d_in[8];
  const float* g1b  = (const float*)d_in[9];
  const float* g2W  = (const float*)d_in[10];
  const float* g2as = (const float*)d_in[11];
  const float* g2ad = (const float*)d_in[12];
  const float* g2b  = (const float*)d_in[13];
  const float* g3W  = (const float*)d_in[14];
  const float* g3as = (const float*)d_in[15];
  const float* g3ad = (const float*)d_in[16];
  const float* g3b  = (const float*)d_in[17];

  const int N = in_sizes[0] / 256;   // 50000
  const int E = in_sizes[1] / 2;     // 800000
  const int Etot = E + N;

  // Workspace layout (floats)
  float* ws = (float*)d_ws;
  size_t off = 0;
  float* bufA = ws + off; off += (size_t)N * 256;  // projection buffer
  float* bufB = ws + off; off += (size_t)N * 256;  // feature buffer (wide)
  float* bufC = ws + off; off += (size_t)N * 128;  // feature buffer (narrow)
  float* alS  = ws + off; off += (size_t)N * 4;
  float* alD  = ws + off; off += (size_t)N * 4;
  int* ibase  = (int*)(ws + off);
  int* deg    = ibase;               // N
  int* rowptr = deg + N;             // N+1
  int* cursor = rowptr + N + 1;      // N
  int* csrsrc = cursor + N;          // Etot

  const int* esrc = ei;
  const int* edst = ei + E;

  dim3 blk16(16, 16);

  // ---- CSR build (edge structure shared by all 3 GAT layers) ----
  zero_int_kernel<<<(N + 255) / 256, 256, 0, stream>>>(deg, N);
  count_deg_kernel<<<(Etot + 255) / 256, 256, 0, stream>>>(edst, deg, E, N);
  scan_kernel<<<1, 1024, 0, stream>>>(deg, rowptr, cursor, N);
  scatter_kernel<<<(Etot + 255) / 256, 256, 0, stream>>>(esrc, edst, cursor,
                                                         csrsrc, E, N);

  // ---- MLP ----
  // h1 = relu(x @ W1 + b1): [N,256]@[256,128] -> bufB
  gemm_kernel<1><<<dim3((N + 63) / 64, 128 / 64), blk16, 0, stream>>>(
      x, W1, b1, bufB, N, 256, 128);
  // h2 = relu(h1 @ W2 + b2): [N,128]@[128,128] -> bufC
  gemm_kernel<1><<<dim3((N + 63) / 64, 128 / 64), blk16, 0, stream>>>(
      bufB, W2, b2, bufC, N, 128, 128);

  // ---- GAT1: 128 -> 4 heads x 64, concat, ELU ----
  gemm_kernel<0><<<dim3((N + 63) / 64, 256 / 64), blk16, 0, stream>>>(
      bufC, g1W, nullptr, bufA, N, 128, 256);
  alpha_kernel<<<(N + 3) / 4, 256, 0, stream>>>(bufA, g1as, g1ad, alS, alD, N,
                                                4, 64);
  gat_agg_kernel<4, 64, true, 1><<<(N + 3) / 4, 256, 0, stream>>>(
      bufA, alS, alD, rowptr, csrsrc, g1b, bufB, N);

  // ---- GAT2: 256 -> 2 heads x 128, mean, ELU ----
  gemm_kernel<0><<<dim3((N + 63) / 64, 256 / 64), blk16, 0, stream>>>(
      bufB, g2W, nullptr, bufA, N, 256, 256);
  alpha_kernel<<<(N + 3) / 4, 256, 0, stream>>>(bufA, g2as, g2ad, alS, alD, N,
                                                2, 128);
  gat_agg_kernel<2, 128, false, 1><<<(N + 3) / 4, 256, 0, stream>>>(
      bufA, alS, alD, rowptr, csrsrc, g2b, bufC, N);

  // ---- GAT3: 128 -> 1 head x 128, mean, no act -> d_out ----
  gemm_kernel<0><<<dim3((N + 63) / 64, 128 / 64), blk16, 0, stream>>>(
      bufC, g3W, nullptr, bufA, N, 128, 128);
  alpha_kernel<<<(N + 3) / 4, 256, 0, stream>>>(bufA, g3as, g3ad, alS, alD, N,
                                                1, 128);
  gat_agg_kernel<1, 128, false, 0><<<(N + 3) / 4, 256, 0, stream>>>(
      bufA, alS, alD, rowptr, csrsrc, g3b, (float*)d_out, N);
}

// Round 3
// 824.330 us; speedup vs baseline: 1.8119x; 1.3061x over previous
//
#include <hip/hip_runtime.h>
#include <math.h>

// ---------------------------------------------------------------------------
// N=50000 nodes, E=800000 edges (+N self-loops), IN=256, HID=128, OUT=128.
// GEMMs run as bf16 MFMA (16x16x32), aggregation in fp32.
// ---------------------------------------------------------------------------

#define NEG_SLOPE 0.2f
#define EPS_DEN 1e-16f

typedef __attribute__((ext_vector_type(8))) short short8;
typedef __attribute__((ext_vector_type(4))) float f32x4;
typedef __attribute__((ext_vector_type(4))) unsigned short u16x4;

__device__ inline unsigned short f2b(float f) {  // RNE float->bf16
  unsigned u = __builtin_bit_cast(unsigned, f);
  unsigned r = (u + 0x7fffu + ((u >> 16) & 1u)) >> 16;
  return (unsigned short)r;
}

__device__ inline void glds16(const void* g, void* l) {
  __builtin_amdgcn_global_load_lds(
      (const __attribute__((address_space(1))) void*)g,
      (__attribute__((address_space(3))) void*)l, 16, 0, 0);
}

// ===========================================================================
// bf16 MFMA GEMM: C[n x M] = act(A[n x K] @ Bt^T + bias)
//   A: bf16 row-major [n_pad x K]; Bt: bf16 row-major [M x K] (pre-transposed)
//   128x128 tile, 4 waves x (64x64), BK=64, global_load_lds staging with
//   XOR-swizzled 16B k-group slots (slot = g ^ (row&7)) -> conflict-free
//   ds_read_b128 fragment loads.  ACT: 0=none 1=relu. OBF: 1 = bf16 out.
// K multiple of 64, M multiple of 128. Rows over-read up to next 128 multiple.
// ===========================================================================
template <int ACT, int OBF>
__global__ __launch_bounds__(256) void mfma_gemm(
    const unsigned short* __restrict__ A, const unsigned short* __restrict__ Bt,
    const float* __restrict__ bias, float* __restrict__ Cf,
    unsigned short* __restrict__ Cb, int n, int K, int M) {
  __shared__ unsigned short As[128 * 64];
  __shared__ unsigned short Bs[128 * 64];

  const int tid = threadIdx.x;
  const int w = tid >> 6, lane = tid & 63;
  const int row0 = blockIdx.x * 128, col0 = blockIdx.y * 128;
  const int lr = lane >> 3, lg = lane & 7;     // staging: local row / slot
  const int lm = lane & 15, kg = lane >> 4;    // fragment lanes
  const int wm = (w >> 1) * 64, wn = (w & 1) * 64;

  f32x4 acc[4][4];
#pragma unroll
  for (int i = 0; i < 4; i++)
#pragma unroll
    for (int j = 0; j < 4; j++) acc[i][j] = {0.f, 0.f, 0.f, 0.f};

  const int swz = (lg ^ lr) << 3;  // global-side swizzled k-offset (elements)

  for (int k0 = 0; k0 < K; k0 += 64) {
    __syncthreads();
#pragma unroll
    for (int it = 0; it < 4; it++) {
      const int r = w * 32 + it * 8;  // tile-local row base of this issue
      glds16(A + (size_t)(row0 + r + lr) * K + k0 + swz, &As[r * 64]);
      glds16(Bt + (size_t)(col0 + r + lr) * K + k0 + swz, &Bs[r * 64]);
    }
    __syncthreads();  // compiler drains vmcnt before s_barrier

#pragma unroll
    for (int kh = 0; kh < 2; kh++) {
      const int sw = ((kh * 4 + kg) ^ (lm & 7)) << 3;
      short8 aF[4], bF[4];
#pragma unroll
      for (int i = 0; i < 4; i++) {
        aF[i] = *(const short8*)&As[(wm + i * 16 + lm) * 64 + sw];
        bF[i] = *(const short8*)&Bs[(wn + i * 16 + lm) * 64 + sw];
      }
#pragma unroll
      for (int i = 0; i < 4; i++)
#pragma unroll
        for (int j = 0; j < 4; j++)
          acc[i][j] = __builtin_amdgcn_mfma_f32_16x16x32_bf16(
              aF[i], bF[j], acc[i][j], 0, 0, 0);
    }
  }

  // epilogue: C/D layout col=lane&15, row=(lane>>4)*4+reg
  const int r4 = (lane >> 4) * 4;
#pragma unroll
  for (int j = 0; j < 4; j++) {
    const int col = col0 + wn + j * 16 + lm;
    const float bv = bias ? bias[col] : 0.f;
#pragma unroll
    for (int i = 0; i < 4; i++) {
#pragma unroll
      for (int r = 0; r < 4; r++) {
        const int row = row0 + wm + i * 16 + r4 + r;
        if (row < n) {
          float v = acc[i][j][r] + bv;
          if (ACT == 1) v = v > 0.f ? v : 0.f;
          if (OBF)
            Cb[(size_t)row * M + col] = f2b(v);
          else
            Cf[(size_t)row * M + col] = v;
        }
      }
    }
  }
}

// ===========================================================================
// fp32 -> bf16 convert (4 elems/thread)
// ===========================================================================
__global__ void convert_bf16_kernel(const float* __restrict__ in,
                                    unsigned short* __restrict__ out,
                                    size_t n) {
  size_t i = ((size_t)blockIdx.x * blockDim.x + threadIdx.x) * 4;
  if (i >= n) return;
  float4 v = *(const float4*)(in + i);
  u16x4 u = {f2b(v.x), f2b(v.y), f2b(v.z), f2b(v.w)};
  *(u16x4*)(out + i) = u;
}

// ===========================================================================
// W [K x M] fp32 -> Wt [M x K] bf16 (32x32 LDS tile)
// ===========================================================================
__global__ void transpose_w_kernel(const float* __restrict__ W,
                                   unsigned short* __restrict__ Wt,
                                   int K, int M) {
  __shared__ float t[32][33];
  const int mb = blockIdx.x * 32, kb = blockIdx.y * 32;
  const int tx = threadIdx.x, ty = threadIdx.y;  // 32 x 8
#pragma unroll
  for (int i = 0; i < 4; i++)
    t[ty + i * 8][tx] = W[(size_t)(kb + ty + i * 8) * M + mb + tx];
  __syncthreads();
#pragma unroll
  for (int i = 0; i < 4; i++)
    Wt[(size_t)(mb + ty + i * 8) * K + kb + tx] = f2b(t[tx][ty + i * 8]);
}

// ===========================================================================
// Per-node attention logits (wave per node, fp32 proj)
// ===========================================================================
__global__ __launch_bounds__(256) void alpha_kernel(
    const float* __restrict__ proj, const float* __restrict__ a_s,
    const float* __restrict__ a_d, float* __restrict__ alpha_s,
    float* __restrict__ alpha_d, int n, int H, int C) {
  int wid = (blockIdx.x * blockDim.x + threadIdx.x) >> 6;
  int lane = threadIdx.x & 63;
  if (wid >= n) return;
  int HC = H * C;
  const float* pr = proj + (size_t)wid * HC;
  float ps[4] = {0.f, 0.f, 0.f, 0.f};
  float pd[4] = {0.f, 0.f, 0.f, 0.f};
  for (int ch = lane; ch < HC; ch += 64) {
    int h = ch / C;
    float v = pr[ch];
    ps[h] += v * a_s[ch];
    pd[h] += v * a_d[ch];
  }
#pragma unroll
  for (int off = 32; off; off >>= 1) {
#pragma unroll
    for (int h = 0; h < 4; h++) {
      ps[h] += __shfl_xor(ps[h], off, 64);
      pd[h] += __shfl_xor(pd[h], off, 64);
    }
  }
  if (lane == 0) {
    for (int h = 0; h < H; h++) {
      alpha_s[(size_t)wid * H + h] = ps[h];
      alpha_d[(size_t)wid * H + h] = pd[h];
    }
  }
}

// ===========================================================================
// CSR build
// ===========================================================================
__global__ void zero_int_kernel(int* __restrict__ p, int n) {
  int i = blockIdx.x * blockDim.x + threadIdx.x;
  if (i < n) p[i] = 0;
}

__global__ void count_deg_kernel(const int* __restrict__ edst,
                                 int* __restrict__ deg, int E, int n) {
  int i = blockIdx.x * blockDim.x + threadIdx.x;
  if (i >= E + n) return;
  int d = (i < E) ? edst[i] : (i - E);
  if ((unsigned)d < (unsigned)n) atomicAdd(&deg[d], 1);
}

__global__ __launch_bounds__(1024) void scan_kernel(
    const int* __restrict__ deg, int* __restrict__ rowptr,
    int* __restrict__ cursor, int n) {
  __shared__ int sums[1024];
  int t = threadIdx.x;
  int chunk = (n + 1023) / 1024;
  int start = t * chunk;
  int end = start + chunk; if (end > n) end = n;
  int s = 0;
  for (int i = start; i < end; i++) s += deg[i];
  sums[t] = s;
  __syncthreads();
  for (int off = 1; off < 1024; off <<= 1) {
    int v = 0;
    if (t >= off) v = sums[t - off];
    __syncthreads();
    if (t >= off) sums[t] += v;
    __syncthreads();
  }
  int excl = (t == 0) ? 0 : sums[t - 1];
  for (int i = start; i < end; i++) {
    rowptr[i] = excl;
    cursor[i] = excl;
    excl += deg[i];
  }
  if (t == 1023) rowptr[n] = sums[1023];
}

__global__ void scatter_kernel(const int* __restrict__ esrc,
                               const int* __restrict__ edst,
                               int* __restrict__ cursor,
                               int* __restrict__ csr_src, int E, int n) {
  int i = blockIdx.x * blockDim.x + threadIdx.x;
  int tot = E + n;
  if (i >= tot) return;
  int s, d;
  if (i < E) { s = esrc[i]; d = edst[i]; } else { s = d = i - E; }
  if ((unsigned)d >= (unsigned)n || (unsigned)s >= (unsigned)n) return;
  int pos = atomicAdd(&cursor[d], 1);
  if (pos < tot) csr_src[pos] = s;
}

// ===========================================================================
// GAT aggregation + segment softmax, edge-parallel subgroups (wave per dst).
// OBF: output bf16 (feeds next GEMM) or fp32 (final).
// ===========================================================================
template <int H, int C, bool CONCAT, int ACT, int OBF>
__global__ __launch_bounds__(256) void gat_agg_kernel(
    const float* __restrict__ proj, const float* __restrict__ alpha_s,
    const float* __restrict__ alpha_d, const int* __restrict__ rowptr,
    const int* __restrict__ csr_src, const float* __restrict__ bias,
    void* __restrict__ out, int n) {
  constexpr int SUBW = C / 4;
  constexpr int NSUB = 64 / SUBW;
  constexpr int HC = H * C;

  const int wid = (blockIdx.x * blockDim.x + threadIdx.x) >> 6;
  const int lane = threadIdx.x & 63;
  if (wid >= n) return;
  const int dst = wid;
  const int sub = lane / SUBW;
  const int sl = lane % SUBW;

  float adv[H];
#pragma unroll
  for (int h = 0; h < H; h++) adv[h] = alpha_d[(size_t)dst * H + h];

  const int rs = rowptr[dst], re = rowptr[dst + 1];

  float m[H];
#pragma unroll
  for (int h = 0; h < H; h++) m[h] = -INFINITY;
  for (int i = rs + lane; i < re; i += 64) {
    int s = csr_src[i];
#pragma unroll
    for (int h = 0; h < H; h++) {
      float e = alpha_s[(size_t)s * H + h] + adv[h];
      e = e > 0.f ? e : NEG_SLOPE * e;
      m[h] = fmaxf(m[h], e);
    }
  }
#pragma unroll
  for (int off = 32; off; off >>= 1)
#pragma unroll
    for (int h = 0; h < H; h++) m[h] = fmaxf(m[h], __shfl_xor(m[h], off, 64));

  float denom[H];
  float4 acc[H];
#pragma unroll
  for (int h = 0; h < H; h++) {
    denom[h] = 0.f;
    acc[h] = make_float4(0.f, 0.f, 0.f, 0.f);
  }
  for (int i = rs + sub; i < re; i += NSUB) {
    int s = csr_src[i];
    const float* pr = proj + (size_t)s * HC + sl * 4;
#pragma unroll
    for (int h = 0; h < H; h++) {
      float e = alpha_s[(size_t)s * H + h] + adv[h];
      e = e > 0.f ? e : NEG_SLOPE * e;
      float ex = __expf(e - m[h]);
      denom[h] += ex;
      float4 pv = *(const float4*)(pr + h * C);
      acc[h].x += ex * pv.x;
      acc[h].y += ex * pv.y;
      acc[h].z += ex * pv.z;
      acc[h].w += ex * pv.w;
    }
  }
#pragma unroll
  for (int off = SUBW; off < 64; off <<= 1) {
#pragma unroll
    for (int h = 0; h < H; h++) {
      denom[h] += __shfl_xor(denom[h], off, 64);
      acc[h].x += __shfl_xor(acc[h].x, off, 64);
      acc[h].y += __shfl_xor(acc[h].y, off, 64);
      acc[h].z += __shfl_xor(acc[h].z, off, 64);
      acc[h].w += __shfl_xor(acc[h].w, off, 64);
    }
  }

  if (sub != 0) return;

  auto store4 = [&](size_t idx, float4 v) {
    if (OBF) {
      u16x4 u = {f2b(v.x), f2b(v.y), f2b(v.z), f2b(v.w)};
      *(u16x4*)((unsigned short*)out + idx) = u;
    } else {
      *(float4*)((float*)out + idx) = v;
    }
  };

  if (CONCAT) {
#pragma unroll
    for (int h = 0; h < H; h++) {
      float inv = 1.f / (denom[h] + EPS_DEN);
      const float4 bv = *(const float4*)(bias + h * C + sl * 4);
      float4 v;
      v.x = acc[h].x * inv + bv.x;
      v.y = acc[h].y * inv + bv.y;
      v.z = acc[h].z * inv + bv.z;
      v.w = acc[h].w * inv + bv.w;
      if (ACT == 1) {
        v.x = v.x > 0.f ? v.x : (__expf(v.x) - 1.f);
        v.y = v.y > 0.f ? v.y : (__expf(v.y) - 1.f);
        v.z = v.z > 0.f ? v.z : (__expf(v.z) - 1.f);
        v.w = v.w > 0.f ? v.w : (__expf(v.w) - 1.f);
      }
      store4((size_t)dst * HC + h * C + sl * 4, v);
    }
  } else {
    float4 sumv = make_float4(0.f, 0.f, 0.f, 0.f);
#pragma unroll
    for (int h = 0; h < H; h++) {
      float inv = 1.f / (denom[h] + EPS_DEN);
      sumv.x += acc[h].x * inv;
      sumv.y += acc[h].y * inv;
      sumv.z += acc[h].z * inv;
      sumv.w += acc[h].w * inv;
    }
    const float invH = 1.f / (float)H;
    const float4 bv = *(const float4*)(bias + sl * 4);
    float4 v;
    v.x = sumv.x * invH + bv.x;
    v.y = sumv.y * invH + bv.y;
    v.z = sumv.z * invH + bv.z;
    v.w = sumv.w * invH + bv.w;
    if (ACT == 1) {
      v.x = v.x > 0.f ? v.x : (__expf(v.x) - 1.f);
      v.y = v.y > 0.f ? v.y : (__expf(v.y) - 1.f);
      v.z = v.z > 0.f ? v.z : (__expf(v.z) - 1.f);
      v.w = v.w > 0.f ? v.w : (__expf(v.w) - 1.f);
    }
    store4((size_t)dst * C + sl * 4, v);
  }
}

// ===========================================================================
// Host side
// ===========================================================================
extern "C" void kernel_launch(void* const* d_in, const int* in_sizes, int n_in,
                              void* d_out, int out_size, void* d_ws,
                              size_t ws_size, hipStream_t stream) {
  const float* x    = (const float*)d_in[0];
  const int*   ei   = (const int*)d_in[1];
  const float* W1   = (const float*)d_in[2];
  const float* b1   = (const float*)d_in[3];
  const float* W2   = (const float*)d_in[4];
  const float* b2   = (const float*)d_in[5];
  const float* g1W  = (const float*)d_in[6];
  const float* g1as = (const float*)d_in[7];
  const float* g1ad = (const float*)d_in[8];
  const float* g1b  = (const float*)d_in[9];
  const float* g2W  = (const float*)d_in[10];
  const float* g2as = (const float*)d_in[11];
  const float* g2ad = (const float*)d_in[12];
  const float* g2b  = (const float*)d_in[13];
  const float* g3W  = (const float*)d_in[14];
  const float* g3as = (const float*)d_in[15];
  const float* g3ad = (const float*)d_in[16];
  const float* g3b  = (const float*)d_in[17];

  const int N = in_sizes[0] / 256;   // 50000
  const int E = in_sizes[1] / 2;     // 800000
  const int Etot = E + N;
  const int NT = (N + 127) / 128;    // row tiles (391)
  const int NP = NT * 128;           // padded rows (50048)

  // ---- workspace layout ----
  char* p = (char*)d_ws;
  float* P = (float*)p;            p += (size_t)N * 256 * 4;   // fp32 proj
  unsigned short* xb  = (unsigned short*)p; p += (size_t)NP * 256 * 2; // x bf16 / act1b
  unsigned short* h1b = (unsigned short*)p; p += (size_t)NP * 128 * 2;
  unsigned short* h2b = (unsigned short*)p; p += (size_t)NP * 128 * 2; // h2 / act2b
  unsigned short* W1t = (unsigned short*)p; p += (size_t)128 * 256 * 2;
  unsigned short* W2t = (unsigned short*)p; p += (size_t)128 * 128 * 2;
  unsigned short* g1Wt = (unsigned short*)p; p += (size_t)256 * 128 * 2;
  unsigned short* g2Wt = (unsigned short*)p; p += (size_t)256 * 256 * 2;
  unsigned short* g3Wt = (unsigned short*)p; p += (size_t)128 * 128 * 2;
  float* alS = (float*)p;          p += (size_t)N * 4 * 4;
  float* alD = (float*)p;          p += (size_t)N * 4 * 4;
  int* deg    = (int*)p;
  int* rowptr = deg + N;
  int* cursor = rowptr + N + 1;
  int* csrsrc = cursor + N;

  const int* esrc = ei;
  const int* edst = ei + E;
  unsigned short* act1b = xb;   // reuse after MLP1 consumed xb
  unsigned short* act2b = h2b;  // reuse after GAT1-proj consumed h2b

  // ---- CSR build ----
  zero_int_kernel<<<(N + 255) / 256, 256, 0, stream>>>(deg, N);
  count_deg_kernel<<<(Etot + 255) / 256, 256, 0, stream>>>(edst, deg, E, N);
  scan_kernel<<<1, 1024, 0, stream>>>(deg, rowptr, cursor, N);
  scatter_kernel<<<(Etot + 255) / 256, 256, 0, stream>>>(esrc, edst, cursor,
                                                         csrsrc, E, N);

  // ---- weight prep (bf16 transposed) + x convert ----
  convert_bf16_kernel<<<((size_t)N * 256 / 4 + 255) / 256, 256, 0, stream>>>(
      x, xb, (size_t)N * 256);
  dim3 tb(32, 8);
  transpose_w_kernel<<<dim3(4, 8), tb, 0, stream>>>(W1, W1t, 256, 128);
  transpose_w_kernel<<<dim3(4, 4), tb, 0, stream>>>(W2, W2t, 128, 128);
  transpose_w_kernel<<<dim3(8, 4), tb, 0, stream>>>(g1W, g1Wt, 128, 256);
  transpose_w_kernel<<<dim3(8, 8), tb, 0, stream>>>(g2W, g2Wt, 256, 256);
  transpose_w_kernel<<<dim3(4, 4), tb, 0, stream>>>(g3W, g3Wt, 128, 128);

  // ---- MLP ----
  mfma_gemm<1, 1><<<dim3(NT, 1), 256, 0, stream>>>(xb, W1t, b1, nullptr, h1b,
                                                   N, 256, 128);
  mfma_gemm<1, 1><<<dim3(NT, 1), 256, 0, stream>>>(h1b, W2t, b2, nullptr, h2b,
                                                   N, 128, 128);

  // ---- GAT1: 128 -> 4 x 64, concat, ELU ----
  mfma_gemm<0, 0><<<dim3(NT, 2), 256, 0, stream>>>(h2b, g1Wt, nullptr, P,
                                                   nullptr, N, 128, 256);
  alpha_kernel<<<(N + 3) / 4, 256, 0, stream>>>(P, g1as, g1ad, alS, alD, N, 4,
                                                64);
  gat_agg_kernel<4, 64, true, 1, 1><<<(N + 3) / 4, 256, 0, stream>>>(
      P, alS, alD, rowptr, csrsrc, g1b, act1b, N);

  // ---- GAT2: 256 -> 2 x 128, mean, ELU ----
  mfma_gemm<0, 0><<<dim3(NT, 2), 256, 0, stream>>>(act1b, g2Wt, nullptr, P,
                                                   nullptr, N, 256, 256);
  alpha_kernel<<<(N + 3) / 4, 256, 0, stream>>>(P, g2as, g2ad, alS, alD, N, 2,
                                                128);
  gat_agg_kernel<2, 128, false, 1, 1><<<(N + 3) / 4, 256, 0, stream>>>(
      P, alS, alD, rowptr, csrsrc, g2b, act2b, N);

  // ---- GAT3: 128 -> 1 x 128, mean, none -> d_out ----
  mfma_gemm<0, 0><<<dim3(NT, 1), 256, 0, stream>>>(act2b, g3Wt, nullptr, P,
                                                   nullptr, N, 128, 128);
  alpha_kernel<<<(N + 3) / 4, 256, 0, stream>>>(P, g3as, g3ad, alS, alD, N, 1,
                                                128);
  gat_agg_kernel<1, 128, false, 0, 0><<<(N + 3) / 4, 256, 0, stream>>>(
      P, alS, alD, rowptr, csrsrc, g3b, d_out, N);
}

// Round 4
// 669.818 us; speedup vs baseline: 2.2298x; 1.2307x over previous
//
#include <hip/hip_runtime.h>
#include <math.h>

// ---------------------------------------------------------------------------
// N=50000 nodes, E=800000 edges (+N self-loops), IN=256, HID=128, OUT=128.
// GEMMs: bf16 MFMA 16x16x32.  Aggregation: bf16 proj rows, fp32 accumulate.
// ---------------------------------------------------------------------------

#define NEG_SLOPE 0.2f
#define EPS_DEN 1e-16f

typedef __attribute__((ext_vector_type(8))) short short8;
typedef __attribute__((ext_vector_type(4))) float f32x4;
typedef __attribute__((ext_vector_type(4))) unsigned short u16x4;

__device__ inline unsigned short f2b(float f) {  // RNE float->bf16
  unsigned u = __builtin_bit_cast(unsigned, f);
  unsigned r = (u + 0x7fffu + ((u >> 16) & 1u)) >> 16;
  return (unsigned short)r;
}
__device__ inline float b2f(unsigned short u) {
  return __builtin_bit_cast(float, (unsigned)u << 16);
}

__device__ inline void glds16(const void* g, void* l) {
  __builtin_amdgcn_global_load_lds(
      (const __attribute__((address_space(1))) void*)g,
      (__attribute__((address_space(3))) void*)l, 16, 0, 0);
}

// ===========================================================================
// bf16 MFMA GEMM: C[n x M] = act(A[n x K] @ Bt^T + bias)
//   128x128 tile, 4 waves x (64x64), BK=64, glds staging w/ XOR swizzle.
//   ACT: 0=none 1=relu.  OBF: 1 = bf16 out, 0 = fp32 out.
// ===========================================================================
template <int ACT, int OBF>
__global__ __launch_bounds__(256) void mfma_gemm(
    const unsigned short* __restrict__ A, const unsigned short* __restrict__ Bt,
    const float* __restrict__ bias, float* __restrict__ Cf,
    unsigned short* __restrict__ Cb, int n, int K, int M) {
  __shared__ unsigned short As[128 * 64];
  __shared__ unsigned short Bs[128 * 64];

  const int tid = threadIdx.x;
  const int w = tid >> 6, lane = tid & 63;
  const int row0 = blockIdx.x * 128, col0 = blockIdx.y * 128;
  const int lr = lane >> 3, lg = lane & 7;
  const int lm = lane & 15, kg = lane >> 4;
  const int wm = (w >> 1) * 64, wn = (w & 1) * 64;

  f32x4 acc[4][4];
#pragma unroll
  for (int i = 0; i < 4; i++)
#pragma unroll
    for (int j = 0; j < 4; j++) acc[i][j] = {0.f, 0.f, 0.f, 0.f};

  const int swz = (lg ^ lr) << 3;

  for (int k0 = 0; k0 < K; k0 += 64) {
    __syncthreads();
#pragma unroll
    for (int it = 0; it < 4; it++) {
      const int r = w * 32 + it * 8;
      glds16(A + (size_t)(row0 + r + lr) * K + k0 + swz, &As[r * 64]);
      glds16(Bt + (size_t)(col0 + r + lr) * K + k0 + swz, &Bs[r * 64]);
    }
    __syncthreads();

#pragma unroll
    for (int kh = 0; kh < 2; kh++) {
      const int sw = ((kh * 4 + kg) ^ (lm & 7)) << 3;
      short8 aF[4], bF[4];
#pragma unroll
      for (int i = 0; i < 4; i++) {
        aF[i] = *(const short8*)&As[(wm + i * 16 + lm) * 64 + sw];
        bF[i] = *(const short8*)&Bs[(wn + i * 16 + lm) * 64 + sw];
      }
#pragma unroll
      for (int i = 0; i < 4; i++)
#pragma unroll
        for (int j = 0; j < 4; j++)
          acc[i][j] = __builtin_amdgcn_mfma_f32_16x16x32_bf16(
              aF[i], bF[j], acc[i][j], 0, 0, 0);
    }
  }

  const int r4 = (lane >> 4) * 4;
#pragma unroll
  for (int j = 0; j < 4; j++) {
    const int col = col0 + wn + j * 16 + lm;
    const float bv = bias ? bias[col] : 0.f;
#pragma unroll
    for (int i = 0; i < 4; i++) {
#pragma unroll
      for (int r = 0; r < 4; r++) {
        const int row = row0 + wm + i * 16 + r4 + r;
        if (row < n) {
          float v = acc[i][j][r] + bv;
          if (ACT == 1) v = v > 0.f ? v : 0.f;
          if (OBF)
            Cb[(size_t)row * M + col] = f2b(v);
          else
            Cf[(size_t)row * M + col] = v;
        }
      }
    }
  }
}

// ===========================================================================
// fp32 -> bf16 convert
// ===========================================================================
__global__ void convert_bf16_kernel(const float* __restrict__ in,
                                    unsigned short* __restrict__ out,
                                    size_t n) {
  size_t i = ((size_t)blockIdx.x * blockDim.x + threadIdx.x) * 4;
  if (i >= n) return;
  float4 v = *(const float4*)(in + i);
  u16x4 u = {f2b(v.x), f2b(v.y), f2b(v.z), f2b(v.w)};
  *(u16x4*)(out + i) = u;
}

// ===========================================================================
// W [K x M] fp32 -> Wt [M x K] bf16
// ===========================================================================
__global__ void transpose_w_kernel(const float* __restrict__ W,
                                   unsigned short* __restrict__ Wt,
                                   int K, int M) {
  __shared__ float t[32][33];
  const int mb = blockIdx.x * 32, kb = blockIdx.y * 32;
  const int tx = threadIdx.x, ty = threadIdx.y;  // 32 x 8
#pragma unroll
  for (int i = 0; i < 4; i++)
    t[ty + i * 8][tx] = W[(size_t)(kb + ty + i * 8) * M + mb + tx];
  __syncthreads();
#pragma unroll
  for (int i = 0; i < 4; i++)
    Wt[(size_t)(mb + ty + i * 8) * K + kb + tx] = f2b(t[tx][ty + i * 8]);
}

// ===========================================================================
// Per-node attention logits from bf16 proj.  One wave per node; lane covers
// 4 channels (u16x4); butterfly within each head's C/4-lane group.
// ===========================================================================
template <int H, int C>
__global__ __launch_bounds__(256) void alpha_kernel(
    const unsigned short* __restrict__ proj, const float* __restrict__ a_s,
    const float* __restrict__ a_d, float* __restrict__ alpha_s,
    float* __restrict__ alpha_d, int n) {
  constexpr int HC = H * C;
  constexpr int GL = C / 4;  // lanes per head group
  const int wid = (blockIdx.x * blockDim.x + threadIdx.x) >> 6;
  const int lane = threadIdx.x & 63;
  if (wid >= n) return;
  const int c0 = lane * 4;
  float ps = 0.f, pd = 0.f;
  if (c0 < HC) {
    u16x4 raw = *(const u16x4*)(proj + (size_t)wid * HC + c0);
    float4 as = *(const float4*)(a_s + c0);
    float4 ad = *(const float4*)(a_d + c0);
    float f0 = b2f(raw.x), f1 = b2f(raw.y), f2 = b2f(raw.z), f3 = b2f(raw.w);
    ps = f0 * as.x + f1 * as.y + f2 * as.z + f3 * as.w;
    pd = f0 * ad.x + f1 * ad.y + f2 * ad.z + f3 * ad.w;
  }
#pragma unroll
  for (int off = 1; off < GL; off <<= 1) {
    ps += __shfl_xor(ps, off, 64);
    pd += __shfl_xor(pd, off, 64);
  }
  if (c0 < HC && (lane % GL) == 0) {
    int h = c0 / C;
    alpha_s[(size_t)wid * H + h] = ps;
    alpha_d[(size_t)wid * H + h] = pd;
  }
}

// ===========================================================================
// CSR build
// ===========================================================================
__global__ void zero_int_kernel(int* __restrict__ p, int n) {
  int i = blockIdx.x * blockDim.x + threadIdx.x;
  if (i < n) p[i] = 0;
}

__global__ void count_deg_kernel(const int* __restrict__ edst,
                                 int* __restrict__ deg, int E, int n) {
  int i = blockIdx.x * blockDim.x + threadIdx.x;
  if (i >= E + n) return;
  int d = (i < E) ? edst[i] : (i - E);
  if ((unsigned)d < (unsigned)n) atomicAdd(&deg[d], 1);
}

__global__ __launch_bounds__(1024) void scan_kernel(
    const int* __restrict__ deg, int* __restrict__ rowptr,
    int* __restrict__ cursor, int n) {
  __shared__ int sums[1024];
  int t = threadIdx.x;
  int chunk = (n + 1023) / 1024;
  int start = t * chunk;
  int end = start + chunk; if (end > n) end = n;
  int s = 0;
  for (int i = start; i < end; i++) s += deg[i];
  sums[t] = s;
  __syncthreads();
  for (int off = 1; off < 1024; off <<= 1) {
    int v = 0;
    if (t >= off) v = sums[t - off];
    __syncthreads();
    if (t >= off) sums[t] += v;
    __syncthreads();
  }
  int excl = (t == 0) ? 0 : sums[t - 1];
  for (int i = start; i < end; i++) {
    rowptr[i] = excl;
    cursor[i] = excl;
    excl += deg[i];
  }
  if (t == 1023) rowptr[n] = sums[1023];
}

__global__ void scatter_kernel(const int* __restrict__ esrc,
                               const int* __restrict__ edst,
                               int* __restrict__ cursor,
                               int* __restrict__ csr_src, int E, int n) {
  int i = blockIdx.x * blockDim.x + threadIdx.x;
  int tot = E + n;
  if (i >= tot) return;
  int s, d;
  if (i < E) { s = esrc[i]; d = edst[i]; } else { s = d = i - E; }
  if ((unsigned)d >= (unsigned)n || (unsigned)s >= (unsigned)n) return;
  int pos = atomicAdd(&cursor[d], 1);
  if (pos < tot) csr_src[pos] = s;
}

// ===========================================================================
// GAT aggregation + segment softmax.  bf16 proj rows, fp32 accumulate.
// Wave per dst; SUBW = C/8 lanes per edge-subgroup (lane = 8 channels/head,
// one short8 16B load per head); NSUB = 64/SUBW edges in flight.
//   C=64 -> 8 edges x 8 lanes;  C=128 -> 4 edges x 16 lanes.
// OBF: 1 = bf16 out (feeds next GEMM), 0 = fp32 out (final).
// ===========================================================================
template <int H, int C, bool CONCAT, int ACT, int OBF>
__global__ __launch_bounds__(256) void gat_agg_kernel(
    const unsigned short* __restrict__ proj, const float* __restrict__ alpha_s,
    const float* __restrict__ alpha_d, const int* __restrict__ rowptr,
    const int* __restrict__ csr_src, const float* __restrict__ bias,
    void* __restrict__ out, int n) {
  constexpr int SUBW = C / 8;
  constexpr int NSUB = 64 / SUBW;
  constexpr int HC = H * C;

  const int wid = (blockIdx.x * blockDim.x + threadIdx.x) >> 6;
  const int lane = threadIdx.x & 63;
  if (wid >= n) return;
  const int dst = wid;
  const int sub = lane / SUBW;
  const int sl = lane % SUBW;  // channels sl*8 .. sl*8+7 of each head

  float adv[H];
#pragma unroll
  for (int h = 0; h < H; h++) adv[h] = alpha_d[(size_t)dst * H + h];

  const int rs = rowptr[dst], re = rowptr[dst + 1];

  // ---- pass 1: per-head segment max (lane-parallel; avg deg ~17 -> 1 iter)
  float m[H];
#pragma unroll
  for (int h = 0; h < H; h++) m[h] = -INFINITY;
  for (int i = rs + lane; i < re; i += 64) {
    int s = csr_src[i];
#pragma unroll
    for (int h = 0; h < H; h++) {
      float e = alpha_s[(size_t)s * H + h] + adv[h];
      e = e > 0.f ? e : NEG_SLOPE * e;
      m[h] = fmaxf(m[h], e);
    }
  }
#pragma unroll
  for (int off = 32; off; off >>= 1)
#pragma unroll
    for (int h = 0; h < H; h++) m[h] = fmaxf(m[h], __shfl_xor(m[h], off, 64));

  // ---- pass 2: subgroup-parallel edge loop, bf16 16B row loads ----
  float denom[H];
  float acc[H][8];
#pragma unroll
  for (int h = 0; h < H; h++) {
    denom[h] = 0.f;
#pragma unroll
    for (int k = 0; k < 8; k++) acc[h][k] = 0.f;
  }
  for (int i = rs + sub; i < re; i += NSUB) {
    int s = csr_src[i];
    const unsigned short* pr = proj + (size_t)s * HC + sl * 8;
#pragma unroll
    for (int h = 0; h < H; h++) {
      float e = alpha_s[(size_t)s * H + h] + adv[h];
      e = e > 0.f ? e : NEG_SLOPE * e;
      float ex = __expf(e - m[h]);
      denom[h] += ex;
      short8 raw = *(const short8*)(pr + h * C);
#pragma unroll
      for (int k = 0; k < 8; k++)
        acc[h][k] += ex * b2f((unsigned short)raw[k]);
    }
  }
#pragma unroll
  for (int off = SUBW; off < 64; off <<= 1) {
#pragma unroll
    for (int h = 0; h < H; h++) {
      denom[h] += __shfl_xor(denom[h], off, 64);
#pragma unroll
      for (int k = 0; k < 8; k++) acc[h][k] += __shfl_xor(acc[h][k], off, 64);
    }
  }

  if (sub != 0) return;

  if (CONCAT) {
#pragma unroll
    for (int h = 0; h < H; h++) {
      float inv = 1.f / (denom[h] + EPS_DEN);
      float vv[8];
#pragma unroll
      for (int k = 0; k < 8; k++) {
        float v = acc[h][k] * inv + bias[h * C + sl * 8 + k];
        if (ACT == 1) v = v > 0.f ? v : (__expf(v) - 1.f);
        vv[k] = v;
      }
      if (OBF) {
        short8 o;
#pragma unroll
        for (int k = 0; k < 8; k++) o[k] = (short)f2b(vv[k]);
        *(short8*)((unsigned short*)out + (size_t)dst * HC + h * C + sl * 8) = o;
      } else {
        float* op = (float*)out + (size_t)dst * HC + h * C + sl * 8;
#pragma unroll
        for (int k = 0; k < 8; k++) op[k] = vv[k];
      }
    }
  } else {
    float inv[H];
#pragma unroll
    for (int h = 0; h < H; h++) inv[h] = 1.f / (denom[h] + EPS_DEN);
    const float invH = 1.f / (float)H;
    float vv[8];
#pragma unroll
    for (int k = 0; k < 8; k++) {
      float s = 0.f;
#pragma unroll
      for (int h = 0; h < H; h++) s += acc[h][k] * inv[h];
      float v = s * invH + bias[sl * 8 + k];
      if (ACT == 1) v = v > 0.f ? v : (__expf(v) - 1.f);
      vv[k] = v;
    }
    if (OBF) {
      short8 o;
#pragma unroll
      for (int k = 0; k < 8; k++) o[k] = (short)f2b(vv[k]);
      *(short8*)((unsigned short*)out + (size_t)dst * C + sl * 8) = o;
    } else {
      float4 v0 = {vv[0], vv[1], vv[2], vv[3]};
      float4 v1 = {vv[4], vv[5], vv[6], vv[7]};
      *(float4*)((float*)out + (size_t)dst * C + sl * 8) = v0;
      *(float4*)((float*)out + (size_t)dst * C + sl * 8 + 4) = v1;
    }
  }
}

// ===========================================================================
// Host side
// ===========================================================================
extern "C" void kernel_launch(void* const* d_in, const int* in_sizes, int n_in,
                              void* d_out, int out_size, void* d_ws,
                              size_t ws_size, hipStream_t stream) {
  const float* x    = (const float*)d_in[0];
  const int*   ei   = (const int*)d_in[1];
  const float* W1   = (const float*)d_in[2];
  const float* b1   = (const float*)d_in[3];
  const float* W2   = (const float*)d_in[4];
  const float* b2   = (const float*)d_in[5];
  const float* g1W  = (const float*)d_in[6];
  const float* g1as = (const float*)d_in[7];
  const float* g1ad = (const float*)d_in[8];
  const float* g1b  = (const float*)d_in[9];
  const float* g2W  = (const float*)d_in[10];
  const float* g2as = (const float*)d_in[11];
  const float* g2ad = (const float*)d_in[12];
  const float* g2b  = (const float*)d_in[13];
  const float* g3W  = (const float*)d_in[14];
  const float* g3as = (const float*)d_in[15];
  const float* g3ad = (const float*)d_in[16];
  const float* g3b  = (const float*)d_in[17];

  const int N = in_sizes[0] / 256;   // 50000
  const int E = in_sizes[1] / 2;     // 800000
  const int Etot = E + N;
  const int NT = (N + 127) / 128;
  const int NP = NT * 128;

  // ---- workspace layout ----
  char* p = (char*)d_ws;
  unsigned short* Pb  = (unsigned short*)p; p += (size_t)NP * 256 * 2;  // bf16 proj
  unsigned short* xb  = (unsigned short*)p; p += (size_t)NP * 256 * 2;  // x / act1b
  unsigned short* h1b = (unsigned short*)p; p += (size_t)NP * 128 * 2;
  unsigned short* h2b = (unsigned short*)p; p += (size_t)NP * 128 * 2;  // h2 / act2b
  unsigned short* W1t = (unsigned short*)p; p += (size_t)128 * 256 * 2;
  unsigned short* W2t = (unsigned short*)p; p += (size_t)128 * 128 * 2;
  unsigned short* g1Wt = (unsigned short*)p; p += (size_t)256 * 128 * 2;
  unsigned short* g2Wt = (unsigned short*)p; p += (size_t)256 * 256 * 2;
  unsigned short* g3Wt = (unsigned short*)p; p += (size_t)128 * 128 * 2;
  float* alS = (float*)p;          p += (size_t)N * 4 * 4;
  float* alD = (float*)p;          p += (size_t)N * 4 * 4;
  int* deg    = (int*)p;
  int* rowptr = deg + N;
  int* cursor = rowptr + N + 1;
  int* csrsrc = cursor + N;

  const int* esrc = ei;
  const int* edst = ei + E;
  unsigned short* act1b = xb;   // reuse after MLP1 consumed xb
  unsigned short* act2b = h2b;  // reuse after GAT1-proj consumed h2b

  // ---- CSR build ----
  zero_int_kernel<<<(N + 255) / 256, 256, 0, stream>>>(deg, N);
  count_deg_kernel<<<(Etot + 255) / 256, 256, 0, stream>>>(edst, deg, E, N);
  scan_kernel<<<1, 1024, 0, stream>>>(deg, rowptr, cursor, N);
  scatter_kernel<<<(Etot + 255) / 256, 256, 0, stream>>>(esrc, edst, cursor,
                                                         csrsrc, E, N);

  // ---- weight prep + x convert ----
  convert_bf16_kernel<<<((size_t)N * 256 / 4 + 255) / 256, 256, 0, stream>>>(
      x, xb, (size_t)N * 256);
  dim3 tb(32, 8);
  transpose_w_kernel<<<dim3(4, 8), tb, 0, stream>>>(W1, W1t, 256, 128);
  transpose_w_kernel<<<dim3(4, 4), tb, 0, stream>>>(W2, W2t, 128, 128);
  transpose_w_kernel<<<dim3(8, 4), tb, 0, stream>>>(g1W, g1Wt, 128, 256);
  transpose_w_kernel<<<dim3(8, 8), tb, 0, stream>>>(g2W, g2Wt, 256, 256);
  transpose_w_kernel<<<dim3(4, 4), tb, 0, stream>>>(g3W, g3Wt, 128, 128);

  // ---- MLP ----
  mfma_gemm<1, 1><<<dim3(NT, 1), 256, 0, stream>>>(xb, W1t, b1, nullptr, h1b,
                                                   N, 256, 128);
  mfma_gemm<1, 1><<<dim3(NT, 1), 256, 0, stream>>>(h1b, W2t, b2, nullptr, h2b,
                                                   N, 128, 128);

  // ---- GAT1: 128 -> 4 x 64, concat, ELU ----
  mfma_gemm<0, 1><<<dim3(NT, 2), 256, 0, stream>>>(h2b, g1Wt, nullptr, nullptr,
                                                   Pb, N, 128, 256);
  alpha_kernel<4, 64><<<(N + 3) / 4, 256, 0, stream>>>(Pb, g1as, g1ad, alS,
                                                       alD, N);
  gat_agg_kernel<4, 64, true, 1, 1><<<(N + 3) / 4, 256, 0, stream>>>(
      Pb, alS, alD, rowptr, csrsrc, g1b, act1b, N);

  // ---- GAT2: 256 -> 2 x 128, mean, ELU ----
  mfma_gemm<0, 1><<<dim3(NT, 2), 256, 0, stream>>>(act1b, g2Wt, nullptr,
                                                   nullptr, Pb, N, 256, 256);
  alpha_kernel<2, 128><<<(N + 3) / 4, 256, 0, stream>>>(Pb, g2as, g2ad, alS,
                                                        alD, N);
  gat_agg_kernel<2, 128, false, 1, 1><<<(N + 3) / 4, 256, 0, stream>>>(
      Pb, alS, alD, rowptr, csrsrc, g2b, act2b, N);

  // ---- GAT3: 128 -> 1 x 128, mean, none -> d_out (fp32) ----
  mfma_gemm<0, 1><<<dim3(NT, 1), 256, 0, stream>>>(act2b, g3Wt, nullptr,
                                                   nullptr, Pb, N, 128, 128);
  alpha_kernel<1, 128><<<(N + 3) / 4, 256, 0, stream>>>(Pb, g3as, g3ad, alS,
                                                        alD, N);
  gat_agg_kernel<1, 128, false, 0, 0><<<(N + 3) / 4, 256, 0, stream>>>(
      Pb, alS, alD, rowptr, csrsrc, g3b, d_out, N);
}

// Round 5
// 612.235 us; speedup vs baseline: 2.4396x; 1.0941x over previous
//
#include <hip/hip_runtime.h>
#include <math.h>

// ---------------------------------------------------------------------------
// N=50000 nodes, E=800000 edges (+N self-loops), IN=256, HID=128, OUT=128.
// GEMMs: bf16 MFMA 16x16x32.  Aggregation: precomputed softmax weights,
// bf16 proj rows, fp32 accumulate, row-spanning subgroups.
// ---------------------------------------------------------------------------

#define NEG_SLOPE 0.2f
#define EPS_DEN 1e-16f

typedef __attribute__((ext_vector_type(8))) short short8;
typedef __attribute__((ext_vector_type(4))) float f32x4;
typedef __attribute__((ext_vector_type(4))) unsigned short u16x4;

__device__ inline unsigned short f2b(float f) {  // RNE float->bf16
  unsigned u = __builtin_bit_cast(unsigned, f);
  unsigned r = (u + 0x7fffu + ((u >> 16) & 1u)) >> 16;
  return (unsigned short)r;
}
__device__ inline float b2f(unsigned short u) {
  return __builtin_bit_cast(float, (unsigned)u << 16);
}

__device__ inline void glds16(const void* g, void* l) {
  __builtin_amdgcn_global_load_lds(
      (const __attribute__((address_space(1))) void*)g,
      (__attribute__((address_space(3))) void*)l, 16, 0, 0);
}

template <int H>
__device__ inline void loadH(const float* p, float* v) {
  if constexpr (H == 4) {
    float4 t = *(const float4*)p;
    v[0] = t.x; v[1] = t.y; v[2] = t.z; v[3] = t.w;
  } else if constexpr (H == 2) {
    float2 t = *(const float2*)p;
    v[0] = t.x; v[1] = t.y;
  } else {
    v[0] = *p;
  }
}
template <int H>
__device__ inline void storeH(float* p, const float* v) {
  if constexpr (H == 4) {
    *(float4*)p = make_float4(v[0], v[1], v[2], v[3]);
  } else if constexpr (H == 2) {
    *(float2*)p = make_float2(v[0], v[1]);
  } else {
    *p = v[0];
  }
}

// ===========================================================================
// bf16 MFMA GEMM: C[n x M] = act(A[n x K] @ Bt^T + bias)
//   128x128 tile, 4 waves x (64x64), BK=64, glds staging w/ XOR swizzle.
// ===========================================================================
template <int ACT, int OBF>
__global__ __launch_bounds__(256) void mfma_gemm(
    const unsigned short* __restrict__ A, const unsigned short* __restrict__ Bt,
    const float* __restrict__ bias, float* __restrict__ Cf,
    unsigned short* __restrict__ Cb, int n, int K, int M) {
  __shared__ unsigned short As[128 * 64];
  __shared__ unsigned short Bs[128 * 64];

  const int tid = threadIdx.x;
  const int w = tid >> 6, lane = tid & 63;
  const int row0 = blockIdx.x * 128, col0 = blockIdx.y * 128;
  const int lr = lane >> 3, lg = lane & 7;
  const int lm = lane & 15, kg = lane >> 4;
  const int wm = (w >> 1) * 64, wn = (w & 1) * 64;

  f32x4 acc[4][4];
#pragma unroll
  for (int i = 0; i < 4; i++)
#pragma unroll
    for (int j = 0; j < 4; j++) acc[i][j] = {0.f, 0.f, 0.f, 0.f};

  const int swz = (lg ^ lr) << 3;

  for (int k0 = 0; k0 < K; k0 += 64) {
    __syncthreads();
#pragma unroll
    for (int it = 0; it < 4; it++) {
      const int r = w * 32 + it * 8;
      glds16(A + (size_t)(row0 + r + lr) * K + k0 + swz, &As[r * 64]);
      glds16(Bt + (size_t)(col0 + r + lr) * K + k0 + swz, &Bs[r * 64]);
    }
    __syncthreads();

#pragma unroll
    for (int kh = 0; kh < 2; kh++) {
      const int sw = ((kh * 4 + kg) ^ (lm & 7)) << 3;
      short8 aF[4], bF[4];
#pragma unroll
      for (int i = 0; i < 4; i++) {
        aF[i] = *(const short8*)&As[(wm + i * 16 + lm) * 64 + sw];
        bF[i] = *(const short8*)&Bs[(wn + i * 16 + lm) * 64 + sw];
      }
#pragma unroll
      for (int i = 0; i < 4; i++)
#pragma unroll
        for (int j = 0; j < 4; j++)
          acc[i][j] = __builtin_amdgcn_mfma_f32_16x16x32_bf16(
              aF[i], bF[j], acc[i][j], 0, 0, 0);
    }
  }

  const int r4 = (lane >> 4) * 4;
#pragma unroll
  for (int j = 0; j < 4; j++) {
    const int col = col0 + wn + j * 16 + lm;
    const float bv = bias ? bias[col] : 0.f;
#pragma unroll
    for (int i = 0; i < 4; i++) {
#pragma unroll
      for (int r = 0; r < 4; r++) {
        const int row = row0 + wm + i * 16 + r4 + r;
        if (row < n) {
          float v = acc[i][j][r] + bv;
          if (ACT == 1) v = v > 0.f ? v : 0.f;
          if (OBF)
            Cb[(size_t)row * M + col] = f2b(v);
          else
            Cf[(size_t)row * M + col] = v;
        }
      }
    }
  }
}

// ===========================================================================
// fp32 -> bf16 convert
// ===========================================================================
__global__ void convert_bf16_kernel(const float* __restrict__ in,
                                    unsigned short* __restrict__ out,
                                    size_t n) {
  size_t i = ((size_t)blockIdx.x * blockDim.x + threadIdx.x) * 4;
  if (i >= n) return;
  float4 v = *(const float4*)(in + i);
  u16x4 u = {f2b(v.x), f2b(v.y), f2b(v.z), f2b(v.w)};
  *(u16x4*)(out + i) = u;
}

// ===========================================================================
// W [K x M] fp32 -> Wt [M x K] bf16
// ===========================================================================
__global__ void transpose_w_kernel(const float* __restrict__ W,
                                   unsigned short* __restrict__ Wt,
                                   int K, int M) {
  __shared__ float t[32][33];
  const int mb = blockIdx.x * 32, kb = blockIdx.y * 32;
  const int tx = threadIdx.x, ty = threadIdx.y;  // 32 x 8
#pragma unroll
  for (int i = 0; i < 4; i++)
    t[ty + i * 8][tx] = W[(size_t)(kb + ty + i * 8) * M + mb + tx];
  __syncthreads();
#pragma unroll
  for (int i = 0; i < 4; i++)
    Wt[(size_t)(mb + ty + i * 8) * K + kb + tx] = f2b(t[tx][ty + i * 8]);
}

// ===========================================================================
// Per-node attention logits from bf16 proj (wave per node)
// ===========================================================================
template <int H, int C>
__global__ __launch_bounds__(256) void alpha_kernel(
    const unsigned short* __restrict__ proj, const float* __restrict__ a_s,
    const float* __restrict__ a_d, float* __restrict__ alpha_s,
    float* __restrict__ alpha_d, int n) {
  constexpr int HC = H * C;
  constexpr int GL = C / 4;  // lanes per head group
  const int wid = (blockIdx.x * blockDim.x + threadIdx.x) >> 6;
  const int lane = threadIdx.x & 63;
  if (wid >= n) return;
  const int c0 = lane * 4;
  float ps = 0.f, pd = 0.f;
  if (c0 < HC) {
    u16x4 raw = *(const u16x4*)(proj + (size_t)wid * HC + c0);
    float4 as = *(const float4*)(a_s + c0);
    float4 ad = *(const float4*)(a_d + c0);
    float f0 = b2f(raw.x), f1 = b2f(raw.y), f2 = b2f(raw.z), f3 = b2f(raw.w);
    ps = f0 * as.x + f1 * as.y + f2 * as.z + f3 * as.w;
    pd = f0 * ad.x + f1 * ad.y + f2 * ad.z + f3 * ad.w;
  }
#pragma unroll
  for (int off = 1; off < GL; off <<= 1) {
    ps += __shfl_xor(ps, off, 64);
    pd += __shfl_xor(pd, off, 64);
  }
  if (c0 < HC && (lane % GL) == 0) {
    int h = c0 / C;
    alpha_s[(size_t)wid * H + h] = ps;
    alpha_d[(size_t)wid * H + h] = pd;
  }
}

// ===========================================================================
// CSR build: histogram -> 3-kernel parallel scan -> scatter
// ===========================================================================
__global__ void zero_int_kernel(int* __restrict__ p, int n) {
  int i = blockIdx.x * blockDim.x + threadIdx.x;
  if (i < n) p[i] = 0;
}

__global__ void count_deg_kernel(const int* __restrict__ edst,
                                 int* __restrict__ deg, int E, int n) {
  int i = blockIdx.x * blockDim.x + threadIdx.x;
  if (i >= E + n) return;
  int d = (i < E) ? edst[i] : (i - E);
  if ((unsigned)d < (unsigned)n) atomicAdd(&deg[d], 1);
}

__global__ __launch_bounds__(256) void block_reduce_kernel(
    const int* __restrict__ deg, int* __restrict__ bsum, int n) {
  __shared__ int s[256];
  const int t = threadIdx.x, i = blockIdx.x * 256 + t;
  s[t] = (i < n) ? deg[i] : 0;
  __syncthreads();
#pragma unroll
  for (int off = 128; off; off >>= 1) {
    if (t < off) s[t] += s[t + off];
    __syncthreads();
  }
  if (t == 0) bsum[blockIdx.x] = s[0];
}

// single block: exclusive scan of <=256 block sums, in place
__global__ __launch_bounds__(256) void scan_bsums_kernel(int* __restrict__ bsum,
                                                         int nb) {
  __shared__ int s[256];
  const int t = threadIdx.x;
  const int v = (t < nb) ? bsum[t] : 0;
  s[t] = v;
  __syncthreads();
#pragma unroll
  for (int off = 1; off < 256; off <<= 1) {
    int a = (t >= off) ? s[t - off] : 0;
    __syncthreads();
    s[t] += a;
    __syncthreads();
  }
  if (t < nb) bsum[t] = s[t] - v;  // exclusive prefix
}

__global__ __launch_bounds__(256) void scan_final_kernel(
    const int* __restrict__ deg, const int* __restrict__ bsumx,
    int* __restrict__ rowptr, int* __restrict__ cursor, int n) {
  __shared__ int s[256];
  const int t = threadIdx.x, i = blockIdx.x * 256 + t;
  const int v = (i < n) ? deg[i] : 0;
  s[t] = v;
  __syncthreads();
#pragma unroll
  for (int off = 1; off < 256; off <<= 1) {
    int a = (t >= off) ? s[t - off] : 0;
    __syncthreads();
    s[t] += a;
    __syncthreads();
  }
  if (i < n) {
    const int base = bsumx[blockIdx.x];
    const int excl = base + s[t] - v;
    rowptr[i] = excl;
    cursor[i] = excl;
    if (i == n - 1) rowptr[n] = base + s[t];
  }
}

__global__ void scatter_kernel(const int* __restrict__ esrc,
                               const int* __restrict__ edst,
                               int* __restrict__ cursor,
                               int* __restrict__ csr_src, int E, int n) {
  int i = blockIdx.x * blockDim.x + threadIdx.x;
  int tot = E + n;
  if (i >= tot) return;
  int s, d;
  if (i < E) { s = esrc[i]; d = edst[i]; } else { s = d = i - E; }
  if ((unsigned)d >= (unsigned)n || (unsigned)s >= (unsigned)n) return;
  int pos = atomicAdd(&cursor[d], 1);
  if (pos < tot) csr_src[pos] = s;
}

// ===========================================================================
// Edge softmax weights: wave per dst, lane-parallel over edges.
// Writes ex=exp(e-m) per (edge,head) to wbuf[i*H+h]; 1/(denom+eps) to dinv.
// Each exp computed exactly once (vs per-subgroup-lane in the agg kernel).
// ===========================================================================
template <int H>
__global__ __launch_bounds__(256) void edge_ex_kernel(
    const float* __restrict__ alpha_s, const float* __restrict__ alpha_d,
    const int* __restrict__ rowptr, const int* __restrict__ csr_src,
    float* __restrict__ wbuf, float* __restrict__ dinv, int n) {
  const int wid = (blockIdx.x * blockDim.x + threadIdx.x) >> 6;
  const int lane = threadIdx.x & 63;
  if (wid >= n) return;
  const int dst = wid;
  float adv[H];
  loadH<H>(alpha_d + (size_t)dst * H, adv);
  const int rs = rowptr[dst], re = rowptr[dst + 1];

  float m[H];
#pragma unroll
  for (int h = 0; h < H; h++) m[h] = -INFINITY;
  for (int i = rs + lane; i < re; i += 64) {
    int s = csr_src[i];
    float as[H];
    loadH<H>(alpha_s + (size_t)s * H, as);
#pragma unroll
    for (int h = 0; h < H; h++) {
      float e = as[h] + adv[h];
      e = e > 0.f ? e : NEG_SLOPE * e;
      m[h] = fmaxf(m[h], e);
    }
  }
#pragma unroll
  for (int off = 32; off; off >>= 1)
#pragma unroll
    for (int h = 0; h < H; h++) m[h] = fmaxf(m[h], __shfl_xor(m[h], off, 64));

  float den[H];
#pragma unroll
  for (int h = 0; h < H; h++) den[h] = 0.f;
  for (int i = rs + lane; i < re; i += 64) {
    int s = csr_src[i];
    float as[H], ex[H];
    loadH<H>(alpha_s + (size_t)s * H, as);
#pragma unroll
    for (int h = 0; h < H; h++) {
      float e = as[h] + adv[h];
      e = e > 0.f ? e : NEG_SLOPE * e;
      ex[h] = __expf(e - m[h]);
      den[h] += ex[h];
    }
    storeH<H>(wbuf + (size_t)i * H, ex);
  }
#pragma unroll
  for (int off = 32; off; off >>= 1)
#pragma unroll
    for (int h = 0; h < H; h++) den[h] += __shfl_xor(den[h], off, 64);

  if (lane == 0) {
    float di[H];
#pragma unroll
    for (int h = 0; h < H; h++) di[h] = 1.f / (den[h] + EPS_DEN);
    storeH<H>(dinv + (size_t)dst * H, di);
  }
}

// ===========================================================================
// GAT aggregation (weights precomputed).  Wave per dst; ROWSPAN=HC/8 lanes
// span the full proj row (8 ch each, one short8/lane); EDGES=64/ROWSPAN
// edges in flight; acc[8]/lane -> tiny log2(EDGES) butterfly.
// ===========================================================================
template <int H, int C, bool CONCAT, int ACT, int OBF>
__global__ __launch_bounds__(256) void gat_agg_kernel(
    const unsigned short* __restrict__ proj, const float* __restrict__ wbuf,
    const float* __restrict__ dinv, const int* __restrict__ rowptr,
    const int* __restrict__ csr_src, const float* __restrict__ bias,
    void* __restrict__ out, int n) {
  constexpr int HC = H * C;
  constexpr int ROWSPAN = HC / 8;      // lanes covering one row (16 or 32)
  constexpr int EDGES = 64 / ROWSPAN;  // edges in flight (2 or 4)
  constexpr int WLANES = C / 8;        // writer lanes in mean mode

  const int wid = (blockIdx.x * blockDim.x + threadIdx.x) >> 6;
  const int lane = threadIdx.x & 63;
  if (wid >= n) return;
  const int dst = wid;
  const int eslot = lane / ROWSPAN;   // which in-flight edge
  const int sl = lane % ROWSPAN;      // row slice: flat channels sl*8..sl*8+7
  const int h_lane = (sl * 8) / C;    // head owning this slice

  const int rs = rowptr[dst], re = rowptr[dst + 1];

  float acc[8];
#pragma unroll
  for (int k = 0; k < 8; k++) acc[k] = 0.f;

  for (int i = rs + eslot; i < re; i += EDGES) {
    const int s = csr_src[i];
    const float w = wbuf[(size_t)i * H + h_lane];
    const short8 raw = *(const short8*)(proj + (size_t)s * HC + sl * 8);
#pragma unroll
    for (int k = 0; k < 8; k++) acc[k] += w * b2f((unsigned short)raw[k]);
  }
  // reduce across edge slots (lanes sl, sl+ROWSPAN, ...)
#pragma unroll
  for (int off = ROWSPAN; off < 64; off <<= 1)
#pragma unroll
    for (int k = 0; k < 8; k++) acc[k] += __shfl_xor(acc[k], off, 64);

  // normalize per head
  const float inv = dinv[(size_t)dst * H + h_lane];
  float v[8];
#pragma unroll
  for (int k = 0; k < 8; k++) v[k] = acc[k] * inv;

  if (!CONCAT && H == 2) {
    // add partner head (lanes sl and sl^16 hold same channel, other head)
#pragma unroll
    for (int k = 0; k < 8; k++) v[k] += __shfl_xor(v[k], 16, 64);
  }

  if (CONCAT) {
    if (eslot != 0) return;
    const int c0 = sl * 8;  // flat h*C+c
    float vv[8];
#pragma unroll
    for (int k = 0; k < 8; k++) {
      float t = v[k] + bias[c0 + k];
      if (ACT == 1) t = t > 0.f ? t : (__expf(t) - 1.f);
      vv[k] = t;
    }
    if (OBF) {
      short8 o;
#pragma unroll
      for (int k = 0; k < 8; k++) o[k] = (short)f2b(vv[k]);
      *(short8*)((unsigned short*)out + (size_t)dst * HC + c0) = o;
    } else {
      float* op = (float*)out + (size_t)dst * HC + c0;
      *(float4*)op = make_float4(vv[0], vv[1], vv[2], vv[3]);
      *(float4*)(op + 4) = make_float4(vv[4], vv[5], vv[6], vv[7]);
    }
  } else {
    if (eslot != 0 || sl >= WLANES) return;
    const int c0 = sl * 8;
    const float invH = 1.f / (float)H;
    float vv[8];
#pragma unroll
    for (int k = 0; k < 8; k++) {
      float t = v[k] * invH + bias[c0 + k];
      if (ACT == 1) t = t > 0.f ? t : (__expf(t) - 1.f);
      vv[k] = t;
    }
    if (OBF) {
      short8 o;
#pragma unroll
      for (int k = 0; k < 8; k++) o[k] = (short)f2b(vv[k]);
      *(short8*)((unsigned short*)out + (size_t)dst * C + c0) = o;
    } else {
      float* op = (float*)out + (size_t)dst * C + c0;
      *(float4*)op = make_float4(vv[0], vv[1], vv[2], vv[3]);
      *(float4*)(op + 4) = make_float4(vv[4], vv[5], vv[6], vv[7]);
    }
  }
}

// ===========================================================================
// Host side
// ===========================================================================
extern "C" void kernel_launch(void* const* d_in, const int* in_sizes, int n_in,
                              void* d_out, int out_size, void* d_ws,
                              size_t ws_size, hipStream_t stream) {
  const float* x    = (const float*)d_in[0];
  const int*   ei   = (const int*)d_in[1];
  const float* W1   = (const float*)d_in[2];
  const float* b1   = (const float*)d_in[3];
  const float* W2   = (const float*)d_in[4];
  const float* b2   = (const float*)d_in[5];
  const float* g1W  = (const float*)d_in[6];
  const float* g1as = (const float*)d_in[7];
  const float* g1ad = (const float*)d_in[8];
  const float* g1b  = (const float*)d_in[9];
  const float* g2W  = (const float*)d_in[10];
  const float* g2as = (const float*)d_in[11];
  const float* g2ad = (const float*)d_in[12];
  const float* g2b  = (const float*)d_in[13];
  const float* g3W  = (const float*)d_in[14];
  const float* g3as = (const float*)d_in[15];
  const float* g3ad = (const float*)d_in[16];
  const float* g3b  = (const float*)d_in[17];

  const int N = in_sizes[0] / 256;   // 50000
  const int E = in_sizes[1] / 2;     // 800000
  const int Etot = E + N;
  const int NT = (N + 127) / 128;
  const int NP = NT * 128;
  const int NB = (N + 255) / 256;    // scan blocks (196 <= 256)

  // ---- workspace layout ----
  char* p = (char*)d_ws;
  unsigned short* Pb  = (unsigned short*)p; p += (size_t)NP * 256 * 2;  // bf16 proj
  unsigned short* xb  = (unsigned short*)p; p += (size_t)NP * 256 * 2;  // x / act1b
  unsigned short* h1b = (unsigned short*)p; p += (size_t)NP * 128 * 2;
  unsigned short* h2b = (unsigned short*)p; p += (size_t)NP * 128 * 2;  // h2 / act2b
  unsigned short* W1t = (unsigned short*)p; p += (size_t)128 * 256 * 2;
  unsigned short* W2t = (unsigned short*)p; p += (size_t)128 * 128 * 2;
  unsigned short* g1Wt = (unsigned short*)p; p += (size_t)256 * 128 * 2;
  unsigned short* g2Wt = (unsigned short*)p; p += (size_t)256 * 256 * 2;
  unsigned short* g3Wt = (unsigned short*)p; p += (size_t)128 * 128 * 2;
  float* alS  = (float*)p; p += (size_t)N * 4 * 4;
  float* alD  = (float*)p; p += (size_t)N * 4 * 4;
  float* wbuf = (float*)p; p += (size_t)Etot * 4 * 4;  // edge softmax weights
  float* dinv = (float*)p; p += (size_t)N * 4 * 4;     // 1/denom per (dst,h)
  int* deg    = (int*)p;
  int* rowptr = deg + N;
  int* cursor = rowptr + N + 1;
  int* bsum   = cursor + N;          // NB block sums
  int* csrsrc = bsum + 256;

  const int* esrc = ei;
  const int* edst = ei + E;
  unsigned short* act1b = xb;   // reuse after MLP1 consumed xb
  unsigned short* act2b = h2b;  // reuse after GAT1-proj consumed h2b

  // ---- CSR build ----
  zero_int_kernel<<<(N + 255) / 256, 256, 0, stream>>>(deg, N);
  count_deg_kernel<<<(Etot + 255) / 256, 256, 0, stream>>>(edst, deg, E, N);
  block_reduce_kernel<<<NB, 256, 0, stream>>>(deg, bsum, N);
  scan_bsums_kernel<<<1, 256, 0, stream>>>(bsum, NB);
  scan_final_kernel<<<NB, 256, 0, stream>>>(deg, bsum, rowptr, cursor, N);
  scatter_kernel<<<(Etot + 255) / 256, 256, 0, stream>>>(esrc, edst, cursor,
                                                         csrsrc, E, N);

  // ---- weight prep + x convert ----
  convert_bf16_kernel<<<((size_t)N * 256 / 4 + 255) / 256, 256, 0, stream>>>(
      x, xb, (size_t)N * 256);
  dim3 tb(32, 8);
  transpose_w_kernel<<<dim3(4, 8), tb, 0, stream>>>(W1, W1t, 256, 128);
  transpose_w_kernel<<<dim3(4, 4), tb, 0, stream>>>(W2, W2t, 128, 128);
  transpose_w_kernel<<<dim3(8, 4), tb, 0, stream>>>(g1W, g1Wt, 128, 256);
  transpose_w_kernel<<<dim3(8, 8), tb, 0, stream>>>(g2W, g2Wt, 256, 256);
  transpose_w_kernel<<<dim3(4, 4), tb, 0, stream>>>(g3W, g3Wt, 128, 128);

  // ---- MLP ----
  mfma_gemm<1, 1><<<dim3(NT, 1), 256, 0, stream>>>(xb, W1t, b1, nullptr, h1b,
                                                   N, 256, 128);
  mfma_gemm<1, 1><<<dim3(NT, 1), 256, 0, stream>>>(h1b, W2t, b2, nullptr, h2b,
                                                   N, 128, 128);

  // ---- GAT1: 128 -> 4 x 64, concat, ELU ----
  mfma_gemm<0, 1><<<dim3(NT, 2), 256, 0, stream>>>(h2b, g1Wt, nullptr, nullptr,
                                                   Pb, N, 128, 256);
  alpha_kernel<4, 64><<<(N + 3) / 4, 256, 0, stream>>>(Pb, g1as, g1ad, alS,
                                                       alD, N);
  edge_ex_kernel<4><<<(N + 3) / 4, 256, 0, stream>>>(alS, alD, rowptr, csrsrc,
                                                     wbuf, dinv, N);
  gat_agg_kernel<4, 64, true, 1, 1><<<(N + 3) / 4, 256, 0, stream>>>(
      Pb, wbuf, dinv, rowptr, csrsrc, g1b, act1b, N);

  // ---- GAT2: 256 -> 2 x 128, mean, ELU ----
  mfma_gemm<0, 1><<<dim3(NT, 2), 256, 0, stream>>>(act1b, g2Wt, nullptr,
                                                   nullptr, Pb, N, 256, 256);
  alpha_kernel<2, 128><<<(N + 3) / 4, 256, 0, stream>>>(Pb, g2as, g2ad, alS,
                                                        alD, N);
  edge_ex_kernel<2><<<(N + 3) / 4, 256, 0, stream>>>(alS, alD, rowptr, csrsrc,
                                                     wbuf, dinv, N);
  gat_agg_kernel<2, 128, false, 1, 1><<<(N + 3) / 4, 256, 0, stream>>>(
      Pb, wbuf, dinv, rowptr, csrsrc, g2b, act2b, N);

  // ---- GAT3: 128 -> 1 x 128, mean, none -> d_out (fp32) ----
  mfma_gemm<0, 1><<<dim3(NT, 1), 256, 0, stream>>>(act2b, g3Wt, nullptr,
                                                   nullptr, Pb, N, 128, 128);
  alpha_kernel<1, 128><<<(N + 3) / 4, 256, 0, stream>>>(Pb, g3as, g3ad, alS,
                                                        alD, N);
  edge_ex_kernel<1><<<(N + 3) / 4, 256, 0, stream>>>(alS, alD, rowptr, csrsrc,
                                                     wbuf, dinv, N);
  gat_agg_kernel<1, 128, false, 0, 0><<<(N + 3) / 4, 256, 0, stream>>>(
      Pb, wbuf, dinv, rowptr, csrsrc, g3b, d_out, N);
}

// Round 6
// 542.032 us; speedup vs baseline: 2.7555x; 1.1295x over previous
//
#include <hip/hip_runtime.h>
#include <math.h>

// ---------------------------------------------------------------------------
// N=50000 nodes, E=800000 edges (+N self-loops), IN=256, HID=128, OUT=128.
// GEMMs: bf16 MFMA 16x16x32.  GAT layer: fused softmax+aggregation kernel
// (per-wave LDS edge-weight staging, no max pass, no global weight buffer).
// ---------------------------------------------------------------------------

#define NEG_SLOPE 0.2f
#define EPS_DEN 1e-16f

typedef __attribute__((ext_vector_type(8))) short short8;
typedef __attribute__((ext_vector_type(4))) float f32x4;
typedef __attribute__((ext_vector_type(4))) unsigned short u16x4;

__device__ inline unsigned short f2b(float f) {  // RNE float->bf16
  unsigned u = __builtin_bit_cast(unsigned, f);
  unsigned r = (u + 0x7fffu + ((u >> 16) & 1u)) >> 16;
  return (unsigned short)r;
}
__device__ inline float b2f(unsigned short u) {
  return __builtin_bit_cast(float, (unsigned)u << 16);
}

__device__ inline void glds16(const void* g, void* l) {
  __builtin_amdgcn_global_load_lds(
      (const __attribute__((address_space(1))) void*)g,
      (__attribute__((address_space(3))) void*)l, 16, 0, 0);
}

template <int H>
__device__ inline void loadH(const float* p, float* v) {
  if constexpr (H == 4) {
    float4 t = *(const float4*)p;
    v[0] = t.x; v[1] = t.y; v[2] = t.z; v[3] = t.w;
  } else if constexpr (H == 2) {
    float2 t = *(const float2*)p;
    v[0] = t.x; v[1] = t.y;
  } else {
    v[0] = *p;
  }
}

// ===========================================================================
// bf16 MFMA GEMM: C[n x M] = act(A[n x K] @ Bt^T + bias)
//   128x128 tile, 4 waves x (64x64), BK=64, glds staging w/ XOR swizzle.
// ===========================================================================
template <int ACT, int OBF>
__global__ __launch_bounds__(256) void mfma_gemm(
    const unsigned short* __restrict__ A, const unsigned short* __restrict__ Bt,
    const float* __restrict__ bias, float* __restrict__ Cf,
    unsigned short* __restrict__ Cb, int n, int K, int M) {
  __shared__ unsigned short As[128 * 64];
  __shared__ unsigned short Bs[128 * 64];

  const int tid = threadIdx.x;
  const int w = tid >> 6, lane = tid & 63;
  const int row0 = blockIdx.x * 128, col0 = blockIdx.y * 128;
  const int lr = lane >> 3, lg = lane & 7;
  const int lm = lane & 15, kg = lane >> 4;
  const int wm = (w >> 1) * 64, wn = (w & 1) * 64;

  f32x4 acc[4][4];
#pragma unroll
  for (int i = 0; i < 4; i++)
#pragma unroll
    for (int j = 0; j < 4; j++) acc[i][j] = {0.f, 0.f, 0.f, 0.f};

  const int swz = (lg ^ lr) << 3;

  for (int k0 = 0; k0 < K; k0 += 64) {
    __syncthreads();
#pragma unroll
    for (int it = 0; it < 4; it++) {
      const int r = w * 32 + it * 8;
      glds16(A + (size_t)(row0 + r + lr) * K + k0 + swz, &As[r * 64]);
      glds16(Bt + (size_t)(col0 + r + lr) * K + k0 + swz, &Bs[r * 64]);
    }
    __syncthreads();

#pragma unroll
    for (int kh = 0; kh < 2; kh++) {
      const int sw = ((kh * 4 + kg) ^ (lm & 7)) << 3;
      short8 aF[4], bF[4];
#pragma unroll
      for (int i = 0; i < 4; i++) {
        aF[i] = *(const short8*)&As[(wm + i * 16 + lm) * 64 + sw];
        bF[i] = *(const short8*)&Bs[(wn + i * 16 + lm) * 64 + sw];
      }
#pragma unroll
      for (int i = 0; i < 4; i++)
#pragma unroll
        for (int j = 0; j < 4; j++)
          acc[i][j] = __builtin_amdgcn_mfma_f32_16x16x32_bf16(
              aF[i], bF[j], acc[i][j], 0, 0, 0);
    }
  }

  const int r4 = (lane >> 4) * 4;
#pragma unroll
  for (int j = 0; j < 4; j++) {
    const int col = col0 + wn + j * 16 + lm;
    const float bv = bias ? bias[col] : 0.f;
#pragma unroll
    for (int i = 0; i < 4; i++) {
#pragma unroll
      for (int r = 0; r < 4; r++) {
        const int row = row0 + wm + i * 16 + r4 + r;
        if (row < n) {
          float v = acc[i][j][r] + bv;
          if (ACT == 1) v = v > 0.f ? v : 0.f;
          if (OBF)
            Cb[(size_t)row * M + col] = f2b(v);
          else
            Cf[(size_t)row * M + col] = v;
        }
      }
    }
  }
}

// ===========================================================================
// fp32 -> bf16 convert
// ===========================================================================
__global__ void convert_bf16_kernel(const float* __restrict__ in,
                                    unsigned short* __restrict__ out,
                                    size_t n) {
  size_t i = ((size_t)blockIdx.x * blockDim.x + threadIdx.x) * 4;
  if (i >= n) return;
  float4 v = *(const float4*)(in + i);
  u16x4 u = {f2b(v.x), f2b(v.y), f2b(v.z), f2b(v.w)};
  *(u16x4*)(out + i) = u;
}

// ===========================================================================
// All 5 weight transposes in ONE launch: W [K x M] fp32 -> Wt [M x K] bf16.
// Descriptor table passed by value; per-block lookup by tile range.
// ===========================================================================
struct TransDescs {
  const float* W[5];
  unsigned short* Wt[5];
  int K[5], M[5];
  int t0[6];  // cumulative 32x32 tile counts
};

__global__ __launch_bounds__(256) void transpose_all_kernel(TransDescs d) {
  __shared__ float t[32][33];
  int b = blockIdx.x;
  int di = 0;
  while (b >= d.t0[di + 1]) di++;
  const int local = b - d.t0[di];
  const int K = d.K[di], M = d.M[di];
  const int mtiles = M / 32;
  const int mb = (local % mtiles) * 32, kb = (local / mtiles) * 32;
  const float* W = d.W[di];
  unsigned short* Wt = d.Wt[di];
  const int tx = threadIdx.x & 31, ty = threadIdx.x >> 5;  // 32 x 8
#pragma unroll
  for (int i = 0; i < 4; i++)
    t[ty + i * 8][tx] = W[(size_t)(kb + ty + i * 8) * M + mb + tx];
  __syncthreads();
#pragma unroll
  for (int i = 0; i < 4; i++)
    Wt[(size_t)(mb + ty + i * 8) * K + kb + tx] = f2b(t[tx][ty + i * 8]);
}

// ===========================================================================
// Per-node attention logits from bf16 proj (wave per node)
// ===========================================================================
template <int H, int C>
__global__ __launch_bounds__(256) void alpha_kernel(
    const unsigned short* __restrict__ proj, const float* __restrict__ a_s,
    const float* __restrict__ a_d, float* __restrict__ alpha_s,
    float* __restrict__ alpha_d, int n) {
  constexpr int HC = H * C;
  constexpr int GL = C / 4;  // lanes per head group
  const int wid = (blockIdx.x * blockDim.x + threadIdx.x) >> 6;
  const int lane = threadIdx.x & 63;
  if (wid >= n) return;
  const int c0 = lane * 4;
  float ps = 0.f, pd = 0.f;
  if (c0 < HC) {
    u16x4 raw = *(const u16x4*)(proj + (size_t)wid * HC + c0);
    float4 as = *(const float4*)(a_s + c0);
    float4 ad = *(const float4*)(a_d + c0);
    float f0 = b2f(raw.x), f1 = b2f(raw.y), f2 = b2f(raw.z), f3 = b2f(raw.w);
    ps = f0 * as.x + f1 * as.y + f2 * as.z + f3 * as.w;
    pd = f0 * ad.x + f1 * ad.y + f2 * ad.z + f3 * ad.w;
  }
#pragma unroll
  for (int off = 1; off < GL; off <<= 1) {
    ps += __shfl_xor(ps, off, 64);
    pd += __shfl_xor(pd, off, 64);
  }
  if (c0 < HC && (lane % GL) == 0) {
    int h = c0 / C;
    alpha_s[(size_t)wid * H + h] = ps;
    alpha_d[(size_t)wid * H + h] = pd;
  }
}

// ===========================================================================
// CSR build: histogram -> 3-kernel parallel scan -> scatter
// ===========================================================================
__global__ void zero_int_kernel(int* __restrict__ p, int n) {
  int i = blockIdx.x * blockDim.x + threadIdx.x;
  if (i < n) p[i] = 0;
}

__global__ void count_deg_kernel(const int* __restrict__ edst,
                                 int* __restrict__ deg, int E, int n) {
  int i = blockIdx.x * blockDim.x + threadIdx.x;
  if (i >= E + n) return;
  int d = (i < E) ? edst[i] : (i - E);
  if ((unsigned)d < (unsigned)n) atomicAdd(&deg[d], 1);
}

__global__ __launch_bounds__(256) void block_reduce_kernel(
    const int* __restrict__ deg, int* __restrict__ bsum, int n) {
  __shared__ int s[256];
  const int t = threadIdx.x, i = blockIdx.x * 256 + t;
  s[t] = (i < n) ? deg[i] : 0;
  __syncthreads();
#pragma unroll
  for (int off = 128; off; off >>= 1) {
    if (t < off) s[t] += s[t + off];
    __syncthreads();
  }
  if (t == 0) bsum[blockIdx.x] = s[0];
}

__global__ __launch_bounds__(256) void scan_bsums_kernel(int* __restrict__ bsum,
                                                         int nb) {
  __shared__ int s[256];
  const int t = threadIdx.x;
  const int v = (t < nb) ? bsum[t] : 0;
  s[t] = v;
  __syncthreads();
#pragma unroll
  for (int off = 1; off < 256; off <<= 1) {
    int a = (t >= off) ? s[t - off] : 0;
    __syncthreads();
    s[t] += a;
    __syncthreads();
  }
  if (t < nb) bsum[t] = s[t] - v;  // exclusive prefix
}

__global__ __launch_bounds__(256) void scan_final_kernel(
    const int* __restrict__ deg, const int* __restrict__ bsumx,
    int* __restrict__ rowptr, int* __restrict__ cursor, int n) {
  __shared__ int s[256];
  const int t = threadIdx.x, i = blockIdx.x * 256 + t;
  const int v = (i < n) ? deg[i] : 0;
  s[t] = v;
  __syncthreads();
#pragma unroll
  for (int off = 1; off < 256; off <<= 1) {
    int a = (t >= off) ? s[t - off] : 0;
    __syncthreads();
    s[t] += a;
    __syncthreads();
  }
  if (i < n) {
    const int base = bsumx[blockIdx.x];
    const int excl = base + s[t] - v;
    rowptr[i] = excl;
    cursor[i] = excl;
    if (i == n - 1) rowptr[n] = base + s[t];
  }
}

__global__ void scatter_kernel(const int* __restrict__ esrc,
                               const int* __restrict__ edst,
                               int* __restrict__ cursor,
                               int* __restrict__ csr_src, int E, int n) {
  int i = blockIdx.x * blockDim.x + threadIdx.x;
  int tot = E + n;
  if (i >= tot) return;
  int s, d;
  if (i < E) { s = esrc[i]; d = edst[i]; } else { s = d = i - E; }
  if ((unsigned)d >= (unsigned)n || (unsigned)s >= (unsigned)n) return;
  int pos = atomicAdd(&cursor[d], 1);
  if (pos < tot) csr_src[pos] = s;
}

// ===========================================================================
// FUSED GAT softmax + aggregation.  Wave per dst.
// Per 64-edge chunk: lanes compute ex=exp(leaky(as+ad)) once per edge
// (lane-parallel) into per-wave LDS + accumulate denom partials in regs;
// then ROWSPAN-lane subgroups (8ch/lane, short8 proj loads) accumulate
// EDGES=64/ROWSPAN edges in flight, reading weights from LDS.
// No max-subtraction (logits are O(1); exp(e)/sum(exp(e)) is exact same
// ratio as the max-shifted form).  No global weight buffers.
// ===========================================================================
template <int H, int C, bool CONCAT, int ACT, int OBF>
__global__ __launch_bounds__(256) void gat_fused_kernel(
    const unsigned short* __restrict__ proj, const float* __restrict__ alpha_s,
    const float* __restrict__ alpha_d, const int* __restrict__ rowptr,
    const int* __restrict__ csr_src, const float* __restrict__ bias,
    void* __restrict__ out, int n) {
  constexpr int HC = H * C;
  constexpr int ROWSPAN = HC / 8;      // lanes covering one row (16 or 32)
  constexpr int EDGES = 64 / ROWSPAN;  // edges in flight (2 or 4)
  constexpr int WLANES = C / 8;        // writer lanes in mean mode

  __shared__ float exs[4][64 * H];  // per-wave chunk of edge weights

  const int wv = threadIdx.x >> 6;
  const int wid = (blockIdx.x * blockDim.x + threadIdx.x) >> 6;
  const int lane = threadIdx.x & 63;
  if (wid >= n) return;
  const int dst = wid;
  const int eslot = lane / ROWSPAN;
  const int sl = lane % ROWSPAN;    // row slice: flat channels sl*8..sl*8+7
  const int h_lane = (sl * 8) / C;  // head owning this slice
  float* myex = &exs[wv][0];

  float adv[H];
  loadH<H>(alpha_d + (size_t)dst * H, adv);
  const int rs = rowptr[dst], re = rowptr[dst + 1];

  float denomp[H];
#pragma unroll
  for (int h = 0; h < H; h++) denomp[h] = 0.f;
  float acc[8];
#pragma unroll
  for (int k = 0; k < 8; k++) acc[k] = 0.f;

  for (int base = rs; base < re; base += 64) {
    const int cnt = min(64, re - base);
    // phase 1: lane-parallel edge weights -> LDS (each exp computed once)
    if (lane < cnt) {
      const int s = csr_src[base + lane];
      float as[H];
      loadH<H>(alpha_s + (size_t)s * H, as);
#pragma unroll
      for (int h = 0; h < H; h++) {
        float e = as[h] + adv[h];
        e = e > 0.f ? e : NEG_SLOPE * e;
        const float ex = __expf(e);
        denomp[h] += ex;
        myex[lane * H + h] = ex;
      }
    }
    __builtin_amdgcn_wave_barrier();  // in-wave LDS write->read ordering
    // phase 2: subgroup-parallel accumulation over this chunk
    for (int j = eslot; j < cnt; j += EDGES) {
      const int s = csr_src[base + j];
      const float w = myex[j * H + h_lane];
      const short8 raw = *(const short8*)(proj + (size_t)s * HC + sl * 8);
#pragma unroll
      for (int k = 0; k < 8; k++) acc[k] += w * b2f((unsigned short)raw[k]);
    }
    __builtin_amdgcn_wave_barrier();
  }

  // full-wave denom reduce; edge-slot acc reduce
#pragma unroll
  for (int off = 32; off; off >>= 1)
#pragma unroll
    for (int h = 0; h < H; h++)
      denomp[h] += __shfl_xor(denomp[h], off, 64);
#pragma unroll
  for (int off = ROWSPAN; off < 64; off <<= 1)
#pragma unroll
    for (int k = 0; k < 8; k++) acc[k] += __shfl_xor(acc[k], off, 64);

  const float inv = 1.f / (denomp[h_lane] + EPS_DEN);
  float v[8];
#pragma unroll
  for (int k = 0; k < 8; k++) v[k] = acc[k] * inv;

  if (!CONCAT && H == 2) {
    // add partner head (lanes sl and sl^16 hold same channel, other head)
#pragma unroll
    for (int k = 0; k < 8; k++) v[k] += __shfl_xor(v[k], 16, 64);
  }

  if (CONCAT) {
    if (eslot != 0) return;
    const int c0 = sl * 8;  // flat h*C+c
    float vv[8];
#pragma unroll
    for (int k = 0; k < 8; k++) {
      float t = v[k] + bias[c0 + k];
      if (ACT == 1) t = t > 0.f ? t : (__expf(t) - 1.f);
      vv[k] = t;
    }
    if (OBF) {
      short8 o;
#pragma unroll
      for (int k = 0; k < 8; k++) o[k] = (short)f2b(vv[k]);
      *(short8*)((unsigned short*)out + (size_t)dst * HC + c0) = o;
    } else {
      float* op = (float*)out + (size_t)dst * HC + c0;
      *(float4*)op = make_float4(vv[0], vv[1], vv[2], vv[3]);
      *(float4*)(op + 4) = make_float4(vv[4], vv[5], vv[6], vv[7]);
    }
  } else {
    if (eslot != 0 || sl >= WLANES) return;
    const int c0 = sl * 8;
    const float invH = 1.f / (float)H;
    float vv[8];
#pragma unroll
    for (int k = 0; k < 8; k++) {
      float t = v[k] * invH + bias[c0 + k];
      if (ACT == 1) t = t > 0.f ? t : (__expf(t) - 1.f);
      vv[k] = t;
    }
    if (OBF) {
      short8 o;
#pragma unroll
      for (int k = 0; k < 8; k++) o[k] = (short)f2b(vv[k]);
      *(short8*)((unsigned short*)out + (size_t)dst * C + c0) = o;
    } else {
      float* op = (float*)out + (size_t)dst * C + c0;
      *(float4*)op = make_float4(vv[0], vv[1], vv[2], vv[3]);
      *(float4*)(op + 4) = make_float4(vv[4], vv[5], vv[6], vv[7]);
    }
  }
}

// ===========================================================================
// Host side
// ===========================================================================
extern "C" void kernel_launch(void* const* d_in, const int* in_sizes, int n_in,
                              void* d_out, int out_size, void* d_ws,
                              size_t ws_size, hipStream_t stream) {
  const float* x    = (const float*)d_in[0];
  const int*   ei   = (const int*)d_in[1];
  const float* W1   = (const float*)d_in[2];
  const float* b1   = (const float*)d_in[3];
  const float* W2   = (const float*)d_in[4];
  const float* b2   = (const float*)d_in[5];
  const float* g1W  = (const float*)d_in[6];
  const float* g1as = (const float*)d_in[7];
  const float* g1ad = (const float*)d_in[8];
  const float* g1b  = (const float*)d_in[9];
  const float* g2W  = (const float*)d_in[10];
  const float* g2as = (const float*)d_in[11];
  const float* g2ad = (const float*)d_in[12];
  const float* g2b  = (const float*)d_in[13];
  const float* g3W  = (const float*)d_in[14];
  const float* g3as = (const float*)d_in[15];
  const float* g3ad = (const float*)d_in[16];
  const float* g3b  = (const float*)d_in[17];

  const int N = in_sizes[0] / 256;   // 50000
  const int E = in_sizes[1] / 2;     // 800000
  const int Etot = E + N;
  const int NT = (N + 127) / 128;
  const int NP = NT * 128;
  const int NB = (N + 255) / 256;    // scan blocks (196 <= 256)

  // ---- workspace layout ----
  char* p = (char*)d_ws;
  unsigned short* Pb  = (unsigned short*)p; p += (size_t)NP * 256 * 2;  // bf16 proj
  unsigned short* xb  = (unsigned short*)p; p += (size_t)NP * 256 * 2;  // x / act1b
  unsigned short* h1b = (unsigned short*)p; p += (size_t)NP * 128 * 2;
  unsigned short* h2b = (unsigned short*)p; p += (size_t)NP * 128 * 2;  // h2 / act2b
  unsigned short* W1t = (unsigned short*)p; p += (size_t)128 * 256 * 2;
  unsigned short* W2t = (unsigned short*)p; p += (size_t)128 * 128 * 2;
  unsigned short* g1Wt = (unsigned short*)p; p += (size_t)256 * 128 * 2;
  unsigned short* g2Wt = (unsigned short*)p; p += (size_t)256 * 256 * 2;
  unsigned short* g3Wt = (unsigned short*)p; p += (size_t)128 * 128 * 2;
  float* alS  = (float*)p; p += (size_t)N * 4 * 4;
  float* alD  = (float*)p; p += (size_t)N * 4 * 4;
  int* deg    = (int*)p;
  int* rowptr = deg + N;
  int* cursor = rowptr + N + 1;
  int* bsum   = cursor + N;          // NB block sums
  int* csrsrc = bsum + 256;

  const int* esrc = ei;
  const int* edst = ei + E;
  unsigned short* act1b = xb;   // reuse after MLP1 consumed xb
  unsigned short* act2b = h2b;  // reuse after GAT1-proj consumed h2b

  // ---- CSR build ----
  zero_int_kernel<<<(N + 255) / 256, 256, 0, stream>>>(deg, N);
  count_deg_kernel<<<(Etot + 255) / 256, 256, 0, stream>>>(edst, deg, E, N);
  block_reduce_kernel<<<NB, 256, 0, stream>>>(deg, bsum, N);
  scan_bsums_kernel<<<1, 256, 0, stream>>>(bsum, NB);
  scan_final_kernel<<<NB, 256, 0, stream>>>(deg, bsum, rowptr, cursor, N);
  scatter_kernel<<<(Etot + 255) / 256, 256, 0, stream>>>(esrc, edst, cursor,
                                                         csrsrc, E, N);

  // ---- weight prep (single launch) + x convert ----
  convert_bf16_kernel<<<((size_t)N * 256 / 4 + 255) / 256, 256, 0, stream>>>(
      x, xb, (size_t)N * 256);
  TransDescs td;
  td.W[0] = W1;  td.Wt[0] = W1t;  td.K[0] = 256; td.M[0] = 128;
  td.W[1] = W2;  td.Wt[1] = W2t;  td.K[1] = 128; td.M[1] = 128;
  td.W[2] = g1W; td.Wt[2] = g1Wt; td.K[2] = 128; td.M[2] = 256;
  td.W[3] = g2W; td.Wt[3] = g2Wt; td.K[3] = 256; td.M[3] = 256;
  td.W[4] = g3W; td.Wt[4] = g3Wt; td.K[4] = 128; td.M[4] = 128;
  td.t0[0] = 0;
  for (int i = 0; i < 5; i++)
    td.t0[i + 1] = td.t0[i] + (td.K[i] / 32) * (td.M[i] / 32);
  transpose_all_kernel<<<td.t0[5], 256, 0, stream>>>(td);

  // ---- MLP ----
  mfma_gemm<1, 1><<<dim3(NT, 1), 256, 0, stream>>>(xb, W1t, b1, nullptr, h1b,
                                                   N, 256, 128);
  mfma_gemm<1, 1><<<dim3(NT, 1), 256, 0, stream>>>(h1b, W2t, b2, nullptr, h2b,
                                                   N, 128, 128);

  // ---- GAT1: 128 -> 4 x 64, concat, ELU ----
  mfma_gemm<0, 1><<<dim3(NT, 2), 256, 0, stream>>>(h2b, g1Wt, nullptr, nullptr,
                                                   Pb, N, 128, 256);
  alpha_kernel<4, 64><<<(N + 3) / 4, 256, 0, stream>>>(Pb, g1as, g1ad, alS,
                                                       alD, N);
  gat_fused_kernel<4, 64, true, 1, 1><<<(N + 3) / 4, 256, 0, stream>>>(
      Pb, alS, alD, rowptr, csrsrc, g1b, act1b, N);

  // ---- GAT2: 256 -> 2 x 128, mean, ELU ----
  mfma_gemm<0, 1><<<dim3(NT, 2), 256, 0, stream>>>(act1b, g2Wt, nullptr,
                                                   nullptr, Pb, N, 256, 256);
  alpha_kernel<2, 128><<<(N + 3) / 4, 256, 0, stream>>>(Pb, g2as, g2ad, alS,
                                                        alD, N);
  gat_fused_kernel<2, 128, false, 1, 1><<<(N + 3) / 4, 256, 0, stream>>>(
      Pb, alS, alD, rowptr, csrsrc, g2b, act2b, N);

  // ---- GAT3: 128 -> 1 x 128, mean, none -> d_out (fp32) ----
  mfma_gemm<0, 1><<<dim3(NT, 1), 256, 0, stream>>>(act2b, g3Wt, nullptr,
                                                   nullptr, Pb, N, 128, 128);
  alpha_kernel<1, 128><<<(N + 3) / 4, 256, 0, stream>>>(Pb, g3as, g3ad, alS,
                                                        alD, N);
  gat_fused_kernel<1, 128, false, 0, 0><<<(N + 3) / 4, 256, 0, stream>>>(
      Pb, alS, alD, rowptr, csrsrc, g3b, d_out, N);
}